// Round 4
// baseline (453.055 us; speedup 1.0000x reference)
//
#include <hip/hip_runtime.h>
#include <math.h>

#define B_ 16
#define H_ 96
#define W_ 96
#define C_ 128
#define HW_ (H_*W_)            // 9216
#define NTOK (B_*HW_)          // 147456
#define NOUT 260

// fused conv tile geometry
#define TH 16
#define TW 32
#define B0H 28
#define B0W 44
#define B1H 26
#define B1W 42
#define B2H 22
#define B2W 38

typedef unsigned short ushort_t;
typedef unsigned int uint_t;
typedef float f32x4 __attribute__((ext_vector_type(4)));
typedef float f32x2 __attribute__((ext_vector_type(2)));
typedef short bfrag __attribute__((ext_vector_type(8)));    // 8 bf16 = 4 VGPRs (MFMA A/B frag)
typedef unsigned short us8 __attribute__((ext_vector_type(8)));

// branch-free erf (Abramowitz-Stegun 7.1.26, |err| <= 1.5e-7) -> gelu
__device__ __forceinline__ float gelu_f(float t) {
    const float x  = t * 0.7071067811865475f;
    const float ax = fabsf(x);
    const float u  = __fdividef(1.0f, fmaf(0.3275911f, ax, 1.0f));
    float p = fmaf(1.061405429f, u, -1.453152027f);
    p = fmaf(p, u, 1.421413741f);
    p = fmaf(p, u, -0.284496736f);
    p = fmaf(p, u, 0.254829592f);
    p = p * u;
    const float e  = __expf(-ax * ax);
    float er = fmaf(-p, e, 1.0f);
    er = (x < 0.0f) ? -er : er;
    return 0.5f * t * (1.0f + er);
}
__device__ __forceinline__ float b2f(ushort_t u) {
    union { unsigned int i; float f; } t; t.i = (unsigned int)u << 16; return t.f;
}
__device__ __forceinline__ ushort_t f2b(float f) {
    union { float f; unsigned int i; } t; t.f = f;
    unsigned int lsb = (t.i >> 16) & 1u;
    t.i += 0x7fffu + lsb;            // round-to-nearest-even
    return (ushort_t)(t.i >> 16);
}
__device__ __forceinline__ void unp2(uint_t u, float& a, float& b) {
    union { unsigned int i; float f; } x, y;
    x.i = u << 16; y.i = u & 0xffff0000u;
    a = x.f; b = y.f;
}
__device__ __forceinline__ void unp8(const uint4 v, float* f) {
    unp2(v.x, f[0], f[1]); unp2(v.y, f[2], f[3]);
    unp2(v.z, f[4], f[5]); unp2(v.w, f[6], f[7]);
}
__device__ __forceinline__ uint_t pk2(float a, float b) {
    return (uint_t)f2b(a) | ((uint_t)f2b(b) << 16);
}
__device__ __forceinline__ uint4 pk8(const float* f) {
    uint4 v;
    v.x = pk2(f[0], f[1]); v.y = pk2(f[2], f[3]);
    v.z = pk2(f[4], f[5]); v.w = pk2(f[6], f[7]);
    return v;
}
// packed (float2) unpack of 8 bf16 channels
__device__ __forceinline__ f32x2 unp2p(uint_t u) {
    union { uint_t i; float f; } a, b;
    a.i = u << 16; b.i = u & 0xffff0000u;
    f32x2 r; r.x = a.f; r.y = b.f; return r;
}
__device__ __forceinline__ void unp8p(const uint4 v, f32x2* d) {
    d[0] = unp2p(v.x); d[1] = unp2p(v.y); d[2] = unp2p(v.z); d[3] = unp2p(v.w);
}

// split fp32 -> bf16 hi/lo (Markidis): a ~= hi + lo, error ~2^-17 |a|
__device__ __forceinline__ void split8_to(const float* f,
                                          ushort_t* __restrict__ hdst,
                                          ushort_t* __restrict__ ldst) {
    us8 vh, vl;
    #pragma unroll
    for (int j = 0; j < 8; ++j) {
        const ushort_t h = f2b(f[j]);
        vh[j] = h;
        vl[j] = f2b(f[j] - b2f(h));
    }
    *(us8*)hdst = vh;
    *(us8*)ldst = vl;
}

// ---------------------------------------------------------------------------
// K0: pack weights into MFMA-B-fragment-native layout, transposed + split.
// pk layout: [mat][hi=0/lo=1][n][k(128)] bf16;
// mat 0 = Wf[:,0:128] (q), 1 = Wf[:,128:256] (ctx), 2 = Wh, 3 = Wp (n=128 each)
// mat 4 = Wf[:,256:260] gate cols padded to n=16 (cols 4..15 zero)
// ---------------------------------------------------------------------------
__global__ __launch_bounds__(128) void pack_weights(
    const float* __restrict__ Wf, const float* __restrict__ Wh,
    const float* __restrict__ Wp, ushort_t* __restrict__ pk)
{
    const int n = blockIdx.x, mat = blockIdx.y, k = threadIdx.x;
    if (mat == 4 && n >= 16) return;
    float v;
    if (mat == 0)      v = Wf[(size_t)k * NOUT + n];
    else if (mat == 1) v = Wf[(size_t)k * NOUT + C_ + n];
    else if (mat == 2) v = Wh[(size_t)k * C_ + n];
    else if (mat == 3) v = Wp[(size_t)k * C_ + n];
    else               v = (n < 4) ? Wf[(size_t)k * NOUT + 2*C_ + n] : 0.0f;
    const ushort_t h = f2b(v);
    const ushort_t l = f2b(v - b2f(h));
    ushort_t* base = pk + (size_t)mat * (2 * C_ * C_);
    const int lo_off = (mat == 4) ? 16 * C_ : C_ * C_;
    base[n * C_ + k] = h;
    base[lo_off + n * C_ + k] = l;
}

// ---------------------------------------------------------------------------
// Per-wave split-bf16 GEMM: 64(tokens) x 32(cols at n0) x K=128.
// acc layout: acc[m][n], D row = m*16 + (lane>>4)*4 + reg, col = n0+n*16+(lane&15)
// ---------------------------------------------------------------------------
template <bool A_LO>
__device__ __forceinline__ void mfma_gemm64(
    const ushort_t (*Ah)[136], const ushort_t (*Al)[136],
    const ushort_t* __restrict__ Bh, const ushort_t* __restrict__ Bl,
    int lane, int n0, f32x4 acc[4][2])
{
    const int ar = lane & 15;               // A row / B col within tile
    const int ak = (lane >> 4) << 3;        // k offset within 32-step
    #pragma unroll
    for (int kk = 0; kk < 4; ++kk) {
        const int kb = (kk << 5) + ak;
        const bfrag bh0 = *(const bfrag*)(Bh + (((n0      + ar) << 7) + kb));
        const bfrag bh1 = *(const bfrag*)(Bh + (((n0 + 16 + ar) << 7) + kb));
        const bfrag bl0 = *(const bfrag*)(Bl + (((n0      + ar) << 7) + kb));
        const bfrag bl1 = *(const bfrag*)(Bl + (((n0 + 16 + ar) << 7) + kb));
        #pragma unroll
        for (int m = 0; m < 4; ++m) {
            const bfrag ah = *(const bfrag*)&Ah[(m << 4) + ar][kb];
            if constexpr (A_LO) {
                const bfrag al = *(const bfrag*)&Al[(m << 4) + ar][kb];
                acc[m][0] = __builtin_amdgcn_mfma_f32_16x16x32_bf16(al, bh0, acc[m][0], 0, 0, 0);
                acc[m][1] = __builtin_amdgcn_mfma_f32_16x16x32_bf16(al, bh1, acc[m][1], 0, 0, 0);
            }
            acc[m][0] = __builtin_amdgcn_mfma_f32_16x16x32_bf16(ah, bl0, acc[m][0], 0, 0, 0);
            acc[m][1] = __builtin_amdgcn_mfma_f32_16x16x32_bf16(ah, bl1, acc[m][1], 0, 0, 0);
            acc[m][0] = __builtin_amdgcn_mfma_f32_16x16x32_bf16(ah, bh0, acc[m][0], 0, 0, 0);
            acc[m][1] = __builtin_amdgcn_mfma_f32_16x16x32_bf16(ah, bh1, acc[m][1], 0, 0, 0);
        }
    }
}

// stage 64x128 fp32 tile -> LDS bf16 hi/lo (coalesced 32B/thread reads)
__device__ __forceinline__ void stage_split_f32(
    const float* __restrict__ src, int tid,
    ushort_t (*Ah)[136], ushort_t (*Al)[136])
{
    #pragma unroll
    for (int p = 0; p < 4; ++p) {
        const int i  = tid + (p << 8);        // 0..1023
        const int t  = i >> 4;                // token row
        const int c8 = (i & 15) << 3;         // k chunk
        const float4 v0 = *(const float4*)(src + (size_t)t * C_ + c8);
        const float4 v1 = *(const float4*)(src + (size_t)t * C_ + c8 + 4);
        const float f[8] = {v0.x, v0.y, v0.z, v0.w, v1.x, v1.y, v1.z, v1.w};
        split8_to(f, &Ah[t][c8], &Al[t][c8]);
    }
}

// ---------------------------------------------------------------------------
// K1: ctx = (x @ Wf)[:, 128:256] + bf ; gates = (x @ Wf)[:, 256:260] + bf
// gates via padded 16-col MFMA tile (mat 4), one tile per wave.
// ---------------------------------------------------------------------------
__global__ __launch_bounds__(256) void gemm_ctx_gates_mfma(
    const float* __restrict__ x, const float* __restrict__ bf,
    const ushort_t* __restrict__ pk,
    ushort_t* __restrict__ ctx, float* __restrict__ gates,
    float* __restrict__ csum)
{
    __shared__ ushort_t Abuf[2][64][136];     // hi / lo (34816 B)
    const int tid  = threadIdx.x;
    const int tok0 = blockIdx.x * 64;
    const int lane = tid & 63;
    const int n0   = (tid >> 6) << 5;         // wave's 32-col strip

    if (blockIdx.x < 8) csum[blockIdx.x * 256 + tid] = 0.0f;

    stage_split_f32(x + (size_t)tok0 * C_, tid, Abuf[0], Abuf[1]);
    __syncthreads();

    f32x4 acc[4][2] = {};
    {
        const ushort_t* Bh = pk + (size_t)1 * (2 * C_ * C_);   // mat 1 = Wf ctx cols
        const ushort_t* Bl = Bh + C_ * C_;
        mfma_gemm64<true>(Abuf[0], Abuf[1], Bh, Bl, lane, n0, acc);
    }

    // gates: wave w computes its own 16-row tile against the padded gate cols
    {
        const int w  = tid >> 6;
        const int ar = lane & 15;
        const int ak = (lane >> 4) << 3;
        const ushort_t* Gh = pk + (size_t)4 * (2 * C_ * C_);
        const ushort_t* Gl = Gh + 16 * C_;
        f32x4 gacc = {};
        #pragma unroll
        for (int kk = 0; kk < 4; ++kk) {
            const int kb = (kk << 5) + ak;
            const bfrag gh = *(const bfrag*)(Gh + ((ar << 7) + kb));
            const bfrag gl = *(const bfrag*)(Gl + ((ar << 7) + kb));
            const bfrag ah = *(const bfrag*)&Abuf[0][(w << 4) + ar][kb];
            const bfrag al = *(const bfrag*)&Abuf[1][(w << 4) + ar][kb];
            gacc = __builtin_amdgcn_mfma_f32_16x16x32_bf16(al, gh, gacc, 0, 0, 0);
            gacc = __builtin_amdgcn_mfma_f32_16x16x32_bf16(ah, gl, gacc, 0, 0, 0);
            gacc = __builtin_amdgcn_mfma_f32_16x16x32_bf16(ah, gh, gacc, 0, 0, 0);
        }
        if (ar < 4) {
            const int rg = (lane >> 4) << 2;
            #pragma unroll
            for (int r = 0; r < 4; ++r)
                gates[(size_t)(tok0 + (w << 4) + rg + r) * 4 + ar] = gacc[r] + bf[2*C_ + ar];
        }
    }
    __syncthreads();   // all LDS reads done before overwrite

    // epilogue: acc + bias -> bf16 into Abuf[0] as ctx_lds[64][136]
    {
        const int ar = lane & 15;
        const int rg = (lane >> 4) << 2;
        #pragma unroll
        for (int n = 0; n < 2; ++n) {
            const int col = n0 + (n << 4) + ar;
            const float bias = bf[C_ + col];
            #pragma unroll
            for (int m = 0; m < 4; ++m)
                #pragma unroll
                for (int r = 0; r < 4; ++r)
                    Abuf[0][(m << 4) + rg + r][col] = f2b(acc[m][n][r] + bias);
        }
    }
    __syncthreads();

    // coalesced transposed store: ctx[colgrp][token][8]
    #pragma unroll
    for (int p = 0; p < 4; ++p) {
        const int i  = tid + (p << 8);
        const int cg = i >> 6;
        const int t  = i & 63;
        *(uint4*)(ctx + (((size_t)cg * NTOK + tok0 + t) << 3))
            = *(const uint4*)&Abuf[0][t][cg << 3];
    }
}

// ---------------------------------------------------------------------------
// K2 (fused): conv3->gelu->conv5->gelu->conv7->gelu cascade in LDS.
// (proven structure; packed f32x2 FMA; fast branch-free gelu)
// ---------------------------------------------------------------------------
__global__ __launch_bounds__(256, 4) void focal_conv_fused(
    const ushort_t* __restrict__ ctx_in,
    const float* __restrict__ k0w, const float* __restrict__ k1w,
    const float* __restrict__ k2w,
    const float* __restrict__ gates,
    ushort_t* __restrict__ ctx_all,
    float* __restrict__ csum)
{
    __shared__ uint4 bufA[B0H*B0W];            // 19712 B (stage0 in; stage2 out 22x38)
    __shared__ uint4 buf1[B1H*B1W];            // 17472 B
    __shared__ float wts[(9+25+49)*8];         //  2656 B   (39840 total)

    const int tid  = threadIdx.x;
    const int cg   = blockIdx.x;               // 0..15 channel group
    const int tile = blockIdx.y;               // 0..17
    const int bb   = blockIdx.z;               // 0..15
    const int wt   = tile % 3, ht = tile / 3;
    const int c0   = cg << 3;
    const int h0   = ht * TH, w0 = wt * TW;

    // weights -> LDS (83 taps x 8 ch)
    if (tid < 166) {
        const int f = tid << 2;
        const float* src; int r;
        if (f < 72)       { r = f;       src = k0w; }
        else if (f < 272) { r = f - 72;  src = k1w; }
        else              { r = f - 272; src = k2w; }
        const int tap = r >> 3, off = r & 7;
        *(float4*)&wts[f] = *(const float4*)(src + tap * C_ + c0 + off);
    }

    // stage 0: global -> bufA (contiguous reads from transposed ctx)
    const ushort_t* cin = ctx_in + (((size_t)cg * NTOK + (size_t)bb * HW_) << 3);
    for (int i = tid; i < B0H*B0W; i += 256) {
        const int r = i / B0W, q = i - r * B0W;
        const int hh = h0 - 6 + r, ww = w0 - 6 + q;
        uint4 v = make_uint4(0u, 0u, 0u, 0u);
        if ((unsigned)hh < (unsigned)H_ && (unsigned)ww < (unsigned)W_)
            v = *(const uint4*)(cin + ((size_t)(hh * W_ + ww) << 3));
        bufA[i] = v;
    }
    __syncthreads();

    // ---- stage 1: buf1 = gelu(conv3(bufA))  [26x42] ----
    {
        int iv[5], ecp[5], boff[5];
        #pragma unroll
        for (int p = 0; p < 5; ++p) {
            const int e = tid + (p << 8);
            iv[p] = (e < B1H*B1W);
            const int ec = iv[p] ? e : 0;
            ecp[p] = ec;
            boff[p] = (ec / B1W) * B0W + (ec % B1W);
        }
        f32x2 acc[5][4] = {};
        #pragma unroll 1
        for (int a = 0; a < 3; ++a) {
            #pragma unroll
            for (int b = 0; b < 3; ++b) {
                f32x2 wv[4];
                #pragma unroll
                for (int c = 0; c < 4; ++c)
                    wv[c] = *(const f32x2*)&wts[(a*3+b)*8 + 2*c];
                const int off = a * B0W + b;
                #pragma unroll
                for (int p = 0; p < 5; ++p) {
                    f32x2 d[4]; unp8p(bufA[boff[p] + off], d);
                    #pragma unroll
                    for (int c = 0; c < 4; ++c)
                        acc[p][c] = __builtin_elementwise_fma(d[c], wv[c], acc[p][c]);
                }
            }
        }
        __syncthreads();   // all bufA reads done before stage2 overwrites it
        #pragma unroll
        for (int p = 0; p < 5; ++p) if (iv[p]) {
            float g[8];
            #pragma unroll
            for (int c = 0; c < 4; ++c) {
                g[2*c]   = gelu_f(acc[p][c].x);
                g[2*c+1] = gelu_f(acc[p][c].y);
            }
            buf1[ecp[p]] = pk8(g);
        }
    }
    __syncthreads();

    // ---- stage 2: bufA = gelu(conv5(buf1))  [22x38] ----
    {
        int iv[4], ecp[4], boff[4];
        #pragma unroll
        for (int p = 0; p < 4; ++p) {
            const int e = tid + (p << 8);
            iv[p] = (e < B2H*B2W);
            const int ec = iv[p] ? e : 0;
            ecp[p] = ec;
            boff[p] = (ec / B2W) * B1W + (ec % B2W);
        }
        f32x2 acc[4][4] = {};
        #pragma unroll 1
        for (int a = 0; a < 5; ++a) {
            #pragma unroll
            for (int b = 0; b < 5; ++b) {
                f32x2 wv[4];
                #pragma unroll
                for (int c = 0; c < 4; ++c)
                    wv[c] = *(const f32x2*)&wts[72 + (a*5+b)*8 + 2*c];
                const int off = a * B1W + b;
                #pragma unroll
                for (int p = 0; p < 4; ++p) {
                    f32x2 d[4]; unp8p(buf1[boff[p] + off], d);
                    #pragma unroll
                    for (int c = 0; c < 4; ++c)
                        acc[p][c] = __builtin_elementwise_fma(d[c], wv[c], acc[p][c]);
                }
            }
        }
        __syncthreads();   // bufA stage-0 data fully dead — safe to overwrite
        #pragma unroll
        for (int p = 0; p < 4; ++p) if (iv[p]) {
            float g[8];
            #pragma unroll
            for (int c = 0; c < 4; ++c) {
                g[2*c]   = gelu_f(acc[p][c].x);
                g[2*c+1] = gelu_f(acc[p][c].y);
            }
            bufA[ecp[p]] = pk8(g);
        }
    }
    __syncthreads();

    // ---- stage 3: ctx3 = gelu(conv7(bufA)); combine 3 gated levels ----
    float lsum[8] = {};
    {
        const int th0 = tid >> 5, tw0 = tid & 31;   // p adds 8 to th
        f32x2 acc[2][4] = {};
        #pragma unroll 1
        for (int a = 0; a < 7; ++a) {
            #pragma unroll
            for (int b = 0; b < 7; ++b) {
                f32x2 wv[4];
                #pragma unroll
                for (int c = 0; c < 4; ++c)
                    wv[c] = *(const f32x2*)&wts[272 + (a*7+b)*8 + 2*c];
                #pragma unroll
                for (int p = 0; p < 2; ++p) {
                    const int th = th0 + (p << 3);
                    f32x2 d[4]; unp8p(bufA[(th + a)*B2W + (tw0 + b)], d);
                    #pragma unroll
                    for (int c = 0; c < 4; ++c)
                        acc[p][c] = __builtin_elementwise_fma(d[c], wv[c], acc[p][c]);
                }
            }
        }
        #pragma unroll
        for (int p = 0; p < 2; ++p) {
            const int th = th0 + (p << 3);
            float ctx3[8];
            #pragma unroll
            for (int c = 0; c < 4; ++c) {
                ctx3[2*c]   = gelu_f(acc[p][c].x);
                ctx3[2*c+1] = gelu_f(acc[p][c].y);
            }
            #pragma unroll
            for (int c = 0; c < 8; ++c) lsum[c] += ctx3[c];
            float d1[8]; unp8(buf1[(5+th)*B1W + (5+tw0)], d1);
            float d2[8]; unp8(bufA[(th+3)*B2W + (tw0+3)], d2);
            const size_t pix = (size_t)bb * HW_ + (size_t)(h0 + th) * W_ + (w0 + tw0);
            const float4 gt = *(const float4*)(gates + pix * 4);
            float o[8];
            #pragma unroll
            for (int c = 0; c < 8; ++c)
                o[c] = d1[c] * gt.x + d2[c] * gt.y + ctx3[c] * gt.z;
            *(uint4*)(ctx_all + pix * C_ + c0) = pk8(o);
        }
    }

    // per-block channel sums of final ctx -> atomic accumulate
    __syncthreads();
    float* red = (float*)bufA;
    #pragma unroll
    for (int c = 0; c < 8; ++c) red[c*256 + tid] = lsum[c];
    __syncthreads();
    for (int off = 128; off > 0; off >>= 1) {
        if (tid < off) {
            #pragma unroll
            for (int c = 0; c < 8; ++c)
                red[c*256 + tid] += red[c*256 + tid + off];
        }
        __syncthreads();
    }
    if (tid < 8) atomicAdd(&csum[bb * C_ + c0 + tid], red[tid * 256]);
}

// ---------------------------------------------------------------------------
// K3: whc[b][n] = sum_k gelu(csum[b][k]/HW) * Wh[k][n]   (rank-1 factor of the
// global-context modulator; replaces per-token cglob staging+split entirely)
// ---------------------------------------------------------------------------
__global__ __launch_bounds__(128) void glob_mod(
    const float* __restrict__ csum, const float* __restrict__ Wh,
    float* __restrict__ whc)
{
    __shared__ float cg[128];
    const int b = blockIdx.x, n = threadIdx.x;
    cg[n] = gelu_f(csum[b * C_ + n] * (1.0f / (float)HW_));
    __syncthreads();
    float s = 0.f;
    #pragma unroll 8
    for (int k = 0; k < C_; ++k)
        s = fmaf(cg[k], Wh[(size_t)k * C_ + n], s);
    whc[b * C_ + n] = s;
}

// ---------------------------------------------------------------------------
// K4 (fused): mod = ctx_all@Wh + g3*whc + bh ; q = x@Wf[:,:C] + bf[:C] ;
// x_out = q*mod ; LayerNorm ; out = xln@Wp + bp   — all in one block pass.
// ctx_all is exact bf16 -> mod GEMM needs A-hi only (no split staging).
// ---------------------------------------------------------------------------
__global__ __launch_bounds__(256) void modq_ln_out_mfma(
    const ushort_t* __restrict__ ctx_all, const float* __restrict__ whc,
    const float* __restrict__ gates, const float* __restrict__ x,
    const ushort_t* __restrict__ pk, const float* __restrict__ bf,
    const float* __restrict__ bh, const float* __restrict__ gamma,
    const float* __restrict__ beta, const float* __restrict__ bp,
    float* __restrict__ out)
{
    __shared__ ushort_t Abuf[2][64][136];     // hi/lo staging; later aliased as xs/xln
    __shared__ float g3s[64];
    __shared__ float whcs[128];
    __shared__ float mu_s[64];
    __shared__ float rs_s[64];
    float (*xs)[132] = (float(*)[132])&Abuf[0][0][0];       // 33792 B <= 34816 B
    ushort_t (*xlnb)[136] = (ushort_t(*)[136])&Abuf[0][0][0];

    const int tid  = threadIdx.x;
    const int tok0 = blockIdx.x * 64;
    const int bidx = tok0 / HW_;
    const int lane = tid & 63;
    const int n0   = (tid >> 6) << 5;
    const int ar   = lane & 15;
    const int rg   = (lane >> 4) << 2;

    // ---- stage ctx_all (bf16, no split) + g3/whc row caches ----
    #pragma unroll
    for (int p = 0; p < 4; ++p) {
        const int i  = tid + (p << 8);
        const int t  = i >> 4;
        const int c8 = (i & 15) << 3;
        *(us8*)&Abuf[0][t][c8] = *(const us8*)(ctx_all + (size_t)(tok0 + t) * C_ + c8);
    }
    if (tid < 64)           g3s[tid]        = gates[(size_t)(tok0 + tid) * 4 + 3];
    else if (tid < 192)     whcs[tid - 64]  = whc[bidx * C_ + (tid - 64)];
    __syncthreads();

    f32x4 am[4][2] = {};
    {
        const ushort_t* Bh2 = pk + (size_t)2 * (2 * C_ * C_);   // mat 2 = Wh
        const ushort_t* Bl2 = Bh2 + C_ * C_;
        mfma_gemm64<false>(Abuf[0], Abuf[0], Bh2, Bl2, lane, n0, am);
    }
    __syncthreads();   // all mod-frag reads done before restaging

    // ---- stage A_q = x, split hi/lo ----
    stage_split_f32(x + (size_t)tok0 * C_, tid, Abuf[0], Abuf[1]);
    __syncthreads();

    f32x4 aq[4][2] = {};
    {
        const ushort_t* Bh0 = pk;                                // mat 0 = Wf q cols
        const ushort_t* Bl0 = Bh0 + C_ * C_;
        mfma_gemm64<true>(Abuf[0], Abuf[1], Bh0, Bl0, lane, n0, aq);
    }
    __syncthreads();   // all q-frag reads done before xs overwrites LDS

    // ---- x_out = (q + bf) * (mod + g3*whc + bh) -> xs ----
    {
        #pragma unroll
        for (int n = 0; n < 2; ++n) {
            const int col = n0 + (n << 4) + ar;
            const float bfv = bf[col];
            const float bhv = bh[col];
            const float whv = whcs[col];
            #pragma unroll
            for (int m = 0; m < 4; ++m)
                #pragma unroll
                for (int r = 0; r < 4; ++r) {
                    const int row = (m << 4) + rg + r;
                    const float mod = am[m][n][r] + g3s[row] * whv + bhv;
                    xs[row][col] = (aq[m][n][r] + bfv) * mod;
                }
        }
    }
    __syncthreads();

    if (tid < 64) {
        float s = 0.f, s2 = 0.f;
        #pragma unroll
        for (int c = 0; c < C_; c += 4) {
            const float4 v = *(const float4*)&xs[tid][c];
            s  += v.x + v.y + v.z + v.w;
            s2 += v.x*v.x + v.y*v.y + v.z*v.z + v.w*v.w;
        }
        const float mu  = s * (1.0f / 128.0f);
        const float var = s2 * (1.0f / 128.0f) - mu * mu;
        mu_s[tid] = mu;
        rs_s[tid] = rsqrtf(var + 0.001f);
    }
    __syncthreads();

    // ---- LN apply into registers (xs still live), then write xln bf16 ----
    {
        const int tt = tid >> 2;
        const int c0b = (tid & 3) << 5;
        const float mu = mu_s[tt], rs = rs_s[tt];
        uint_t xw[16];
        #pragma unroll
        for (int j = 0; j < 8; ++j) {
            const int c = c0b + (j << 2);
            const float4 v  = *(const float4*)&xs[tt][c];
            const float4 gm = *(const float4*)(gamma + c);
            const float4 bt = *(const float4*)(beta + c);
            xw[2*j]   = pk2((v.x - mu) * rs * gm.x + bt.x,
                            (v.y - mu) * rs * gm.y + bt.y);
            xw[2*j+1] = pk2((v.z - mu) * rs * gm.z + bt.z,
                            (v.w - mu) * rs * gm.w + bt.w);
        }
        __syncthreads();   // all xs reads complete before overwrite
        #pragma unroll
        for (int j = 0; j < 4; ++j)
            *(uint4*)&xlnb[tt][c0b + (j << 3)] = *(uint4*)&xw[4*j];
    }
    __syncthreads();

    // ---- out = xln @ Wp + bp ----
    f32x4 ao[4][2] = {};
    {
        const ushort_t* Bh3 = pk + (size_t)3 * (2 * C_ * C_);   // mat 3 = Wp
        const ushort_t* Bl3 = Bh3 + C_ * C_;
        mfma_gemm64<false>((const ushort_t(*)[136])xlnb,
                           (const ushort_t(*)[136])xlnb, Bh3, Bl3, lane, n0, ao);
    }
    {
        #pragma unroll
        for (int n = 0; n < 2; ++n) {
            const int col = n0 + (n << 4) + ar;
            const float bpv = bp[col];
            #pragma unroll
            for (int m = 0; m < 4; ++m)
                #pragma unroll
                for (int r = 0; r < 4; ++r) {
                    const int row = (m << 4) + rg + r;
                    out[(size_t)(tok0 + row) * C_ + col] = ao[m][n][r] + bpv;
                }
        }
    }
}

// ---------------------------------------------------------------------------
extern "C" void kernel_launch(void* const* d_in, const int* in_sizes, int n_in,
                              void* d_out, int out_size, void* d_ws, size_t ws_size,
                              hipStream_t stream) {
    const float* x     = (const float*)d_in[0];
    const float* Wf    = (const float*)d_in[1];
    const float* bf    = (const float*)d_in[2];
    const float* Wh    = (const float*)d_in[3];
    const float* bh    = (const float*)d_in[4];
    const float* gamma = (const float*)d_in[5];
    const float* beta  = (const float*)d_in[6];
    const float* Wp    = (const float*)d_in[7];
    const float* bp    = (const float*)d_in[8];
    const float* k0    = (const float*)d_in[9];
    const float* k1    = (const float*)d_in[10];
    const float* k2    = (const float*)d_in[11];
    float* out = (float*)d_out;

    const size_t NC = (size_t)NTOK * C_;
    ushort_t* P0  = (ushort_t*)d_ws;          // ctx transposed
    ushort_t* ACC = P0 + NC;                  // ctx_all (token-major)
    float* gates  = (float*)(ACC + NC);
    float* csum   = gates + (size_t)NTOK * 4;
    float* whc    = csum + (size_t)B_ * C_;
    ushort_t* pkw = (ushort_t*)(whc + (size_t)B_ * C_);  // 4x(2x128x128) + 2x16x128 bf16

    pack_weights<<<dim3(C_, 5), 128, 0, stream>>>(Wf, Wh, Wp, pkw);
    gemm_ctx_gates_mfma<<<NTOK / 64, 256, 0, stream>>>(x, bf, pkw, P0, gates, csum);
    focal_conv_fused<<<dim3(C_/8, (H_/TH)*(W_/TW), B_), 256, 0, stream>>>(
        P0, k0, k1, k2, gates, ACC, csum);
    glob_mod<<<B_, 128, 0, stream>>>(csum, Wh, whc);
    modq_ln_out_mfma<<<NTOK / 64, 256, 0, stream>>>(
        ACC, whc, gates, x, pkw, bf, bh, gamma, beta, bp, out);
}

// Round 5
// 428.107 us; speedup vs baseline: 1.0583x; 1.0583x over previous
//
#include <hip/hip_runtime.h>
#include <math.h>

#define B_ 16
#define H_ 96
#define W_ 96
#define C_ 128
#define HW_ (H_*W_)            // 9216
#define NTOK (B_*HW_)          // 147456
#define NOUT 260

// fused conv tile geometry
#define TH 16
#define TW 32
#define B0H 28
#define B0W 44
#define B1H 26
#define B1W 42
#define B2H 22
#define B2W 38

typedef unsigned short ushort_t;
typedef unsigned int uint_t;
typedef float f32x4 __attribute__((ext_vector_type(4)));
typedef float f32x2 __attribute__((ext_vector_type(2)));
typedef short bfrag __attribute__((ext_vector_type(8)));    // 8 bf16 = 4 VGPRs (MFMA A/B frag)
typedef unsigned short us8 __attribute__((ext_vector_type(8)));

// branch-free erf (Abramowitz-Stegun 7.1.26, |err| <= 1.5e-7) -> gelu.
// Native v_rcp_f32 / v_exp_f32 via builtins (NO IEEE div expansion — the
// round-4 regression was __fdividef lowering to div_scale/div_fmas/div_fixup).
__device__ __forceinline__ float gelu_f(float t) {
    const float x  = t * 0.7071067811865475f;
    const float ax = fabsf(x);
    const float u  = __builtin_amdgcn_rcpf(fmaf(0.3275911f, ax, 1.0f));
    float p = fmaf(1.061405429f, u, -1.453152027f);
    p = fmaf(p, u, 1.421413741f);
    p = fmaf(p, u, -0.284496736f);
    p = fmaf(p, u, 0.254829592f);
    p = p * u;
    const float e  = __builtin_amdgcn_exp2f(ax * ax * -1.4426950408889634f);
    const float er = fmaf(-p, e, 1.0f);            // erf(|x|) in [0,1)
    union { float f; uint_t i; } ux, ue;
    ux.f = x; ue.f = er;
    ue.i |= (ux.i & 0x80000000u);                  // copysign(er, x)
    return 0.5f * t * (1.0f + ue.f);
}
__device__ __forceinline__ float b2f(ushort_t u) {
    union { unsigned int i; float f; } t; t.i = (unsigned int)u << 16; return t.f;
}
__device__ __forceinline__ ushort_t f2b(float f) {
    union { float f; unsigned int i; } t; t.f = f;
    unsigned int lsb = (t.i >> 16) & 1u;
    t.i += 0x7fffu + lsb;            // round-to-nearest-even
    return (ushort_t)(t.i >> 16);
}
__device__ __forceinline__ void unp2(uint_t u, float& a, float& b) {
    union { unsigned int i; float f; } x, y;
    x.i = u << 16; y.i = u & 0xffff0000u;
    a = x.f; b = y.f;
}
__device__ __forceinline__ void unp8(const uint4 v, float* f) {
    unp2(v.x, f[0], f[1]); unp2(v.y, f[2], f[3]);
    unp2(v.z, f[4], f[5]); unp2(v.w, f[6], f[7]);
}
__device__ __forceinline__ uint_t pk2(float a, float b) {
    return (uint_t)f2b(a) | ((uint_t)f2b(b) << 16);
}
__device__ __forceinline__ uint4 pk8(const float* f) {
    uint4 v;
    v.x = pk2(f[0], f[1]); v.y = pk2(f[2], f[3]);
    v.z = pk2(f[4], f[5]); v.w = pk2(f[6], f[7]);
    return v;
}
// packed (float2) unpack of 8 bf16 channels
__device__ __forceinline__ f32x2 unp2p(uint_t u) {
    union { uint_t i; float f; } a, b;
    a.i = u << 16; b.i = u & 0xffff0000u;
    f32x2 r; r.x = a.f; r.y = b.f; return r;
}
__device__ __forceinline__ void unp8p(const uint4 v, f32x2* d) {
    d[0] = unp2p(v.x); d[1] = unp2p(v.y); d[2] = unp2p(v.z); d[3] = unp2p(v.w);
}

// split fp32 -> bf16 hi/lo (Markidis): a ~= hi + lo, error ~2^-17 |a|
__device__ __forceinline__ void split8_to(const float* f,
                                          ushort_t* __restrict__ hdst,
                                          ushort_t* __restrict__ ldst) {
    us8 vh, vl;
    #pragma unroll
    for (int j = 0; j < 8; ++j) {
        const ushort_t h = f2b(f[j]);
        vh[j] = h;
        vl[j] = f2b(f[j] - b2f(h));
    }
    *(us8*)hdst = vh;
    *(us8*)ldst = vl;
}

// ---------------------------------------------------------------------------
// K0: pack weights into MFMA-B-fragment-native layout, transposed + split.
// pk layout: [mat][hi=0/lo=1][n][k(128)] bf16;
// mat 0 = Wf[:,0:128] (q), 1 = Wf[:,128:256] (ctx), 2 = Wh, 3 = Wp (n=128 each)
// mat 4 = Wf[:,256:260] gate cols padded to n=16 (cols 4..15 zero)
// ---------------------------------------------------------------------------
__global__ __launch_bounds__(128) void pack_weights(
    const float* __restrict__ Wf, const float* __restrict__ Wh,
    const float* __restrict__ Wp, ushort_t* __restrict__ pk)
{
    const int n = blockIdx.x, mat = blockIdx.y, k = threadIdx.x;
    if (mat == 4 && n >= 16) return;
    float v;
    if (mat == 0)      v = Wf[(size_t)k * NOUT + n];
    else if (mat == 1) v = Wf[(size_t)k * NOUT + C_ + n];
    else if (mat == 2) v = Wh[(size_t)k * C_ + n];
    else if (mat == 3) v = Wp[(size_t)k * C_ + n];
    else               v = (n < 4) ? Wf[(size_t)k * NOUT + 2*C_ + n] : 0.0f;
    const ushort_t h = f2b(v);
    const ushort_t l = f2b(v - b2f(h));
    ushort_t* base = pk + (size_t)mat * (2 * C_ * C_);
    const int lo_off = (mat == 4) ? 16 * C_ : C_ * C_;
    base[n * C_ + k] = h;
    base[lo_off + n * C_ + k] = l;
}

// ---------------------------------------------------------------------------
// Per-wave split-bf16 GEMM: 64(tokens) x 32(cols at n0) x K=128.
// acc layout: acc[m][n], D row = m*16 + (lane>>4)*4 + reg, col = n0+n*16+(lane&15)
// ---------------------------------------------------------------------------
template <bool A_LO>
__device__ __forceinline__ void mfma_gemm64(
    const ushort_t (*Ah)[136], const ushort_t (*Al)[136],
    const ushort_t* __restrict__ Bh, const ushort_t* __restrict__ Bl,
    int lane, int n0, f32x4 acc[4][2])
{
    const int ar = lane & 15;               // A row / B col within tile
    const int ak = (lane >> 4) << 3;        // k offset within 32-step
    #pragma unroll
    for (int kk = 0; kk < 4; ++kk) {
        const int kb = (kk << 5) + ak;
        const bfrag bh0 = *(const bfrag*)(Bh + (((n0      + ar) << 7) + kb));
        const bfrag bh1 = *(const bfrag*)(Bh + (((n0 + 16 + ar) << 7) + kb));
        const bfrag bl0 = *(const bfrag*)(Bl + (((n0      + ar) << 7) + kb));
        const bfrag bl1 = *(const bfrag*)(Bl + (((n0 + 16 + ar) << 7) + kb));
        #pragma unroll
        for (int m = 0; m < 4; ++m) {
            const bfrag ah = *(const bfrag*)&Ah[(m << 4) + ar][kb];
            if constexpr (A_LO) {
                const bfrag al = *(const bfrag*)&Al[(m << 4) + ar][kb];
                acc[m][0] = __builtin_amdgcn_mfma_f32_16x16x32_bf16(al, bh0, acc[m][0], 0, 0, 0);
                acc[m][1] = __builtin_amdgcn_mfma_f32_16x16x32_bf16(al, bh1, acc[m][1], 0, 0, 0);
            }
            acc[m][0] = __builtin_amdgcn_mfma_f32_16x16x32_bf16(ah, bl0, acc[m][0], 0, 0, 0);
            acc[m][1] = __builtin_amdgcn_mfma_f32_16x16x32_bf16(ah, bl1, acc[m][1], 0, 0, 0);
            acc[m][0] = __builtin_amdgcn_mfma_f32_16x16x32_bf16(ah, bh0, acc[m][0], 0, 0, 0);
            acc[m][1] = __builtin_amdgcn_mfma_f32_16x16x32_bf16(ah, bh1, acc[m][1], 0, 0, 0);
        }
    }
}

// stage 64x128 fp32 tile -> LDS bf16 hi/lo (coalesced 32B/thread reads)
__device__ __forceinline__ void stage_split_f32(
    const float* __restrict__ src, int tid,
    ushort_t (*Ah)[136], ushort_t (*Al)[136])
{
    #pragma unroll
    for (int p = 0; p < 4; ++p) {
        const int i  = tid + (p << 8);        // 0..1023
        const int t  = i >> 4;                // token row
        const int c8 = (i & 15) << 3;         // k chunk
        const float4 v0 = *(const float4*)(src + (size_t)t * C_ + c8);
        const float4 v1 = *(const float4*)(src + (size_t)t * C_ + c8 + 4);
        const float f[8] = {v0.x, v0.y, v0.z, v0.w, v1.x, v1.y, v1.z, v1.w};
        split8_to(f, &Ah[t][c8], &Al[t][c8]);
    }
}

// ---------------------------------------------------------------------------
// K1: ctx = (x @ Wf)[:, 128:256] + bf ; gates = (x @ Wf)[:, 256:260] + bf
// gates via padded 16-col MFMA tile (mat 4), one tile per wave.
// ---------------------------------------------------------------------------
__global__ __launch_bounds__(256) void gemm_ctx_gates_mfma(
    const float* __restrict__ x, const float* __restrict__ bf,
    const ushort_t* __restrict__ pk,
    ushort_t* __restrict__ ctx, float* __restrict__ gates,
    float* __restrict__ csum)
{
    __shared__ ushort_t Abuf[2][64][136];     // hi / lo (34816 B)
    const int tid  = threadIdx.x;
    const int tok0 = blockIdx.x * 64;
    const int lane = tid & 63;
    const int n0   = (tid >> 6) << 5;         // wave's 32-col strip

    if (blockIdx.x < 8) csum[blockIdx.x * 256 + tid] = 0.0f;

    stage_split_f32(x + (size_t)tok0 * C_, tid, Abuf[0], Abuf[1]);
    __syncthreads();

    f32x4 acc[4][2] = {};
    {
        const ushort_t* Bh = pk + (size_t)1 * (2 * C_ * C_);   // mat 1 = Wf ctx cols
        const ushort_t* Bl = Bh + C_ * C_;
        mfma_gemm64<true>(Abuf[0], Abuf[1], Bh, Bl, lane, n0, acc);
    }

    // gates: wave w computes its own 16-row tile against the padded gate cols
    {
        const int w  = tid >> 6;
        const int ar = lane & 15;
        const int ak = (lane >> 4) << 3;
        const ushort_t* Gh = pk + (size_t)4 * (2 * C_ * C_);
        const ushort_t* Gl = Gh + 16 * C_;
        f32x4 gacc = {};
        #pragma unroll
        for (int kk = 0; kk < 4; ++kk) {
            const int kb = (kk << 5) + ak;
            const bfrag gh = *(const bfrag*)(Gh + ((ar << 7) + kb));
            const bfrag gl = *(const bfrag*)(Gl + ((ar << 7) + kb));
            const bfrag ah = *(const bfrag*)&Abuf[0][(w << 4) + ar][kb];
            const bfrag al = *(const bfrag*)&Abuf[1][(w << 4) + ar][kb];
            gacc = __builtin_amdgcn_mfma_f32_16x16x32_bf16(al, gh, gacc, 0, 0, 0);
            gacc = __builtin_amdgcn_mfma_f32_16x16x32_bf16(ah, gl, gacc, 0, 0, 0);
            gacc = __builtin_amdgcn_mfma_f32_16x16x32_bf16(ah, gh, gacc, 0, 0, 0);
        }
        if (ar < 4) {
            const int rg = (lane >> 4) << 2;
            #pragma unroll
            for (int r = 0; r < 4; ++r)
                gates[(size_t)(tok0 + (w << 4) + rg + r) * 4 + ar] = gacc[r] + bf[2*C_ + ar];
        }
    }
    __syncthreads();   // all LDS reads done before overwrite

    // epilogue: acc + bias -> bf16 into Abuf[0] as ctx_lds[64][136]
    {
        const int ar = lane & 15;
        const int rg = (lane >> 4) << 2;
        #pragma unroll
        for (int n = 0; n < 2; ++n) {
            const int col = n0 + (n << 4) + ar;
            const float bias = bf[C_ + col];
            #pragma unroll
            for (int m = 0; m < 4; ++m)
                #pragma unroll
                for (int r = 0; r < 4; ++r)
                    Abuf[0][(m << 4) + rg + r][col] = f2b(acc[m][n][r] + bias);
        }
    }
    __syncthreads();

    // coalesced transposed store: ctx[colgrp][token][8]
    #pragma unroll
    for (int p = 0; p < 4; ++p) {
        const int i  = tid + (p << 8);
        const int cg = i >> 6;
        const int t  = i & 63;
        *(uint4*)(ctx + (((size_t)cg * NTOK + tok0 + t) << 3))
            = *(const uint4*)&Abuf[0][t][cg << 3];
    }
}

// ---------------------------------------------------------------------------
// K2 (fused): conv3->gelu->conv5->gelu->conv7->gelu cascade in LDS.
// (proven structure; packed f32x2 FMA; native-op branch-free gelu)
// ---------------------------------------------------------------------------
__global__ __launch_bounds__(256, 4) void focal_conv_fused(
    const ushort_t* __restrict__ ctx_in,
    const float* __restrict__ k0w, const float* __restrict__ k1w,
    const float* __restrict__ k2w,
    const float* __restrict__ gates,
    ushort_t* __restrict__ ctx_all,
    float* __restrict__ csum)
{
    __shared__ uint4 bufA[B0H*B0W];            // 19712 B (stage0 in; stage2 out 22x38)
    __shared__ uint4 buf1[B1H*B1W];            // 17472 B
    __shared__ float wts[(9+25+49)*8];         //  2656 B   (39840 total)

    const int tid  = threadIdx.x;
    const int cg   = blockIdx.x;               // 0..15 channel group
    const int tile = blockIdx.y;               // 0..17
    const int bb   = blockIdx.z;               // 0..15
    const int wt   = tile % 3, ht = tile / 3;
    const int c0   = cg << 3;
    const int h0   = ht * TH, w0 = wt * TW;

    // weights -> LDS (83 taps x 8 ch)
    if (tid < 166) {
        const int f = tid << 2;
        const float* src; int r;
        if (f < 72)       { r = f;       src = k0w; }
        else if (f < 272) { r = f - 72;  src = k1w; }
        else              { r = f - 272; src = k2w; }
        const int tap = r >> 3, off = r & 7;
        *(float4*)&wts[f] = *(const float4*)(src + tap * C_ + c0 + off);
    }

    // stage 0: global -> bufA (contiguous reads from transposed ctx)
    const ushort_t* cin = ctx_in + (((size_t)cg * NTOK + (size_t)bb * HW_) << 3);
    for (int i = tid; i < B0H*B0W; i += 256) {
        const int r = i / B0W, q = i - r * B0W;
        const int hh = h0 - 6 + r, ww = w0 - 6 + q;
        uint4 v = make_uint4(0u, 0u, 0u, 0u);
        if ((unsigned)hh < (unsigned)H_ && (unsigned)ww < (unsigned)W_)
            v = *(const uint4*)(cin + ((size_t)(hh * W_ + ww) << 3));
        bufA[i] = v;
    }
    __syncthreads();

    // ---- stage 1: buf1 = gelu(conv3(bufA))  [26x42] ----
    {
        int iv[5], ecp[5], boff[5];
        #pragma unroll
        for (int p = 0; p < 5; ++p) {
            const int e = tid + (p << 8);
            iv[p] = (e < B1H*B1W);
            const int ec = iv[p] ? e : 0;
            ecp[p] = ec;
            boff[p] = (ec / B1W) * B0W + (ec % B1W);
        }
        f32x2 acc[5][4] = {};
        #pragma unroll 1
        for (int a = 0; a < 3; ++a) {
            #pragma unroll
            for (int b = 0; b < 3; ++b) {
                f32x2 wv[4];
                #pragma unroll
                for (int c = 0; c < 4; ++c)
                    wv[c] = *(const f32x2*)&wts[(a*3+b)*8 + 2*c];
                const int off = a * B0W + b;
                #pragma unroll
                for (int p = 0; p < 5; ++p) {
                    f32x2 d[4]; unp8p(bufA[boff[p] + off], d);
                    #pragma unroll
                    for (int c = 0; c < 4; ++c)
                        acc[p][c] = __builtin_elementwise_fma(d[c], wv[c], acc[p][c]);
                }
            }
        }
        __syncthreads();   // all bufA reads done before stage2 overwrites it
        #pragma unroll
        for (int p = 0; p < 5; ++p) if (iv[p]) {
            float g[8];
            #pragma unroll
            for (int c = 0; c < 4; ++c) {
                g[2*c]   = gelu_f(acc[p][c].x);
                g[2*c+1] = gelu_f(acc[p][c].y);
            }
            buf1[ecp[p]] = pk8(g);
        }
    }
    __syncthreads();

    // ---- stage 2: bufA = gelu(conv5(buf1))  [22x38] ----
    {
        int iv[4], ecp[4], boff[4];
        #pragma unroll
        for (int p = 0; p < 4; ++p) {
            const int e = tid + (p << 8);
            iv[p] = (e < B2H*B2W);
            const int ec = iv[p] ? e : 0;
            ecp[p] = ec;
            boff[p] = (ec / B2W) * B1W + (ec % B2W);
        }
        f32x2 acc[4][4] = {};
        #pragma unroll 1
        for (int a = 0; a < 5; ++a) {
            #pragma unroll
            for (int b = 0; b < 5; ++b) {
                f32x2 wv[4];
                #pragma unroll
                for (int c = 0; c < 4; ++c)
                    wv[c] = *(const f32x2*)&wts[72 + (a*5+b)*8 + 2*c];
                const int off = a * B1W + b;
                #pragma unroll
                for (int p = 0; p < 4; ++p) {
                    f32x2 d[4]; unp8p(buf1[boff[p] + off], d);
                    #pragma unroll
                    for (int c = 0; c < 4; ++c)
                        acc[p][c] = __builtin_elementwise_fma(d[c], wv[c], acc[p][c]);
                }
            }
        }
        __syncthreads();   // bufA stage-0 data fully dead — safe to overwrite
        #pragma unroll
        for (int p = 0; p < 4; ++p) if (iv[p]) {
            float g[8];
            #pragma unroll
            for (int c = 0; c < 4; ++c) {
                g[2*c]   = gelu_f(acc[p][c].x);
                g[2*c+1] = gelu_f(acc[p][c].y);
            }
            bufA[ecp[p]] = pk8(g);
        }
    }
    __syncthreads();

    // ---- stage 3: ctx3 = gelu(conv7(bufA)); combine 3 gated levels ----
    float lsum[8] = {};
    {
        const int th0 = tid >> 5, tw0 = tid & 31;   // p adds 8 to th
        f32x2 acc[2][4] = {};
        #pragma unroll 1
        for (int a = 0; a < 7; ++a) {
            #pragma unroll
            for (int b = 0; b < 7; ++b) {
                f32x2 wv[4];
                #pragma unroll
                for (int c = 0; c < 4; ++c)
                    wv[c] = *(const f32x2*)&wts[272 + (a*7+b)*8 + 2*c];
                #pragma unroll
                for (int p = 0; p < 2; ++p) {
                    const int th = th0 + (p << 3);
                    f32x2 d[4]; unp8p(bufA[(th + a)*B2W + (tw0 + b)], d);
                    #pragma unroll
                    for (int c = 0; c < 4; ++c)
                        acc[p][c] = __builtin_elementwise_fma(d[c], wv[c], acc[p][c]);
                }
            }
        }
        #pragma unroll
        for (int p = 0; p < 2; ++p) {
            const int th = th0 + (p << 3);
            float ctx3[8];
            #pragma unroll
            for (int c = 0; c < 4; ++c) {
                ctx3[2*c]   = gelu_f(acc[p][c].x);
                ctx3[2*c+1] = gelu_f(acc[p][c].y);
            }
            #pragma unroll
            for (int c = 0; c < 8; ++c) lsum[c] += ctx3[c];
            float d1[8]; unp8(buf1[(5+th)*B1W + (5+tw0)], d1);
            float d2[8]; unp8(bufA[(th+3)*B2W + (tw0+3)], d2);
            const size_t pix = (size_t)bb * HW_ + (size_t)(h0 + th) * W_ + (w0 + tw0);
            const float4 gt = *(const float4*)(gates + pix * 4);
            float o[8];
            #pragma unroll
            for (int c = 0; c < 8; ++c)
                o[c] = d1[c] * gt.x + d2[c] * gt.y + ctx3[c] * gt.z;
            *(uint4*)(ctx_all + pix * C_ + c0) = pk8(o);
        }
    }

    // per-block channel sums of final ctx -> atomic accumulate
    __syncthreads();
    float* red = (float*)bufA;
    #pragma unroll
    for (int c = 0; c < 8; ++c) red[c*256 + tid] = lsum[c];
    __syncthreads();
    for (int off = 128; off > 0; off >>= 1) {
        if (tid < off) {
            #pragma unroll
            for (int c = 0; c < 8; ++c)
                red[c*256 + tid] += red[c*256 + tid + off];
        }
        __syncthreads();
    }
    if (tid < 8) atomicAdd(&csum[bb * C_ + c0 + tid], red[tid * 256]);
}

// ---------------------------------------------------------------------------
// K3: whc[b][n] = sum_k gelu(csum[b][k]/HW) * Wh[k][n]   (rank-1 factor of the
// global-context modulator; replaces per-token cglob staging+split entirely)
// ---------------------------------------------------------------------------
__global__ __launch_bounds__(128) void glob_mod(
    const float* __restrict__ csum, const float* __restrict__ Wh,
    float* __restrict__ whc)
{
    __shared__ float cg[128];
    const int b = blockIdx.x, n = threadIdx.x;
    cg[n] = gelu_f(csum[b * C_ + n] * (1.0f / (float)HW_));
    __syncthreads();
    float s = 0.f;
    #pragma unroll 8
    for (int k = 0; k < C_; ++k)
        s = fmaf(cg[k], Wh[(size_t)k * C_ + n], s);
    whc[b * C_ + n] = s;
}

// ---------------------------------------------------------------------------
// K4 (fused): mod = ctx_all@Wh + g3*whc + bh ; q = x@Wf[:,:C] + bf[:C] ;
// x_out = q*mod ; LayerNorm ; out = xln@Wp + bp   — all in one block pass.
// ctx_all is exact bf16 -> mod GEMM needs A-hi only (no split staging).
// ---------------------------------------------------------------------------
__global__ __launch_bounds__(256) void modq_ln_out_mfma(
    const ushort_t* __restrict__ ctx_all, const float* __restrict__ whc,
    const float* __restrict__ gates, const float* __restrict__ x,
    const ushort_t* __restrict__ pk, const float* __restrict__ bf,
    const float* __restrict__ bh, const float* __restrict__ gamma,
    const float* __restrict__ beta, const float* __restrict__ bp,
    float* __restrict__ out)
{
    __shared__ ushort_t Abuf[2][64][136];     // hi/lo staging; later aliased as xs/xln
    __shared__ float g3s[64];
    __shared__ float whcs[128];
    __shared__ float mu_s[64];
    __shared__ float rs_s[64];
    float (*xs)[132] = (float(*)[132])&Abuf[0][0][0];       // 33792 B <= 34816 B
    ushort_t (*xlnb)[136] = (ushort_t(*)[136])&Abuf[0][0][0];

    const int tid  = threadIdx.x;
    const int tok0 = blockIdx.x * 64;
    const int bidx = tok0 / HW_;
    const int lane = tid & 63;
    const int n0   = (tid >> 6) << 5;
    const int ar   = lane & 15;
    const int rg   = (lane >> 4) << 2;

    // ---- stage ctx_all (bf16, no split) + g3/whc row caches ----
    #pragma unroll
    for (int p = 0; p < 4; ++p) {
        const int i  = tid + (p << 8);
        const int t  = i >> 4;
        const int c8 = (i & 15) << 3;
        *(us8*)&Abuf[0][t][c8] = *(const us8*)(ctx_all + (size_t)(tok0 + t) * C_ + c8);
    }
    if (tid < 64)           g3s[tid]        = gates[(size_t)(tok0 + tid) * 4 + 3];
    else if (tid < 192)     whcs[tid - 64]  = whc[bidx * C_ + (tid - 64)];
    __syncthreads();

    f32x4 am[4][2] = {};
    {
        const ushort_t* Bh2 = pk + (size_t)2 * (2 * C_ * C_);   // mat 2 = Wh
        const ushort_t* Bl2 = Bh2 + C_ * C_;
        mfma_gemm64<false>(Abuf[0], Abuf[0], Bh2, Bl2, lane, n0, am);
    }
    __syncthreads();   // all mod-frag reads done before restaging

    // ---- stage A_q = x, split hi/lo ----
    stage_split_f32(x + (size_t)tok0 * C_, tid, Abuf[0], Abuf[1]);
    __syncthreads();

    f32x4 aq[4][2] = {};
    {
        const ushort_t* Bh0 = pk;                                // mat 0 = Wf q cols
        const ushort_t* Bl0 = Bh0 + C_ * C_;
        mfma_gemm64<true>(Abuf[0], Abuf[1], Bh0, Bl0, lane, n0, aq);
    }
    __syncthreads();   // all q-frag reads done before xs overwrites LDS

    // ---- x_out = (q + bf) * (mod + g3*whc + bh) -> xs ----
    {
        #pragma unroll
        for (int n = 0; n < 2; ++n) {
            const int col = n0 + (n << 4) + ar;
            const float bfv = bf[col];
            const float bhv = bh[col];
            const float whv = whcs[col];
            #pragma unroll
            for (int m = 0; m < 4; ++m)
                #pragma unroll
                for (int r = 0; r < 4; ++r) {
                    const int row = (m << 4) + rg + r;
                    const float mod = am[m][n][r] + g3s[row] * whv + bhv;
                    xs[row][col] = (aq[m][n][r] + bfv) * mod;
                }
        }
    }
    __syncthreads();

    if (tid < 64) {
        float s = 0.f, s2 = 0.f;
        #pragma unroll
        for (int c = 0; c < C_; c += 4) {
            const float4 v = *(const float4*)&xs[tid][c];
            s  += v.x + v.y + v.z + v.w;
            s2 += v.x*v.x + v.y*v.y + v.z*v.z + v.w*v.w;
        }
        const float mu  = s * (1.0f / 128.0f);
        const float var = s2 * (1.0f / 128.0f) - mu * mu;
        mu_s[tid] = mu;
        rs_s[tid] = rsqrtf(var + 0.001f);
    }
    __syncthreads();

    // ---- LN apply into registers (xs still live), then write xln bf16 ----
    {
        const int tt = tid >> 2;
        const int c0b = (tid & 3) << 5;
        const float mu = mu_s[tt], rs = rs_s[tt];
        uint_t xw[16];
        #pragma unroll
        for (int j = 0; j < 8; ++j) {
            const int c = c0b + (j << 2);
            const float4 v  = *(const float4*)&xs[tt][c];
            const float4 gm = *(const float4*)(gamma + c);
            const float4 bt = *(const float4*)(beta + c);
            xw[2*j]   = pk2((v.x - mu) * rs * gm.x + bt.x,
                            (v.y - mu) * rs * gm.y + bt.y);
            xw[2*j+1] = pk2((v.z - mu) * rs * gm.z + bt.z,
                            (v.w - mu) * rs * gm.w + bt.w);
        }
        __syncthreads();   // all xs reads complete before overwrite
        #pragma unroll
        for (int j = 0; j < 4; ++j)
            *(uint4*)&xlnb[tt][c0b + (j << 3)] = *(uint4*)&xw[4*j];
    }
    __syncthreads();

    // ---- out = xln @ Wp + bp ----
    f32x4 ao[4][2] = {};
    {
        const ushort_t* Bh3 = pk + (size_t)3 * (2 * C_ * C_);   // mat 3 = Wp
        const ushort_t* Bl3 = Bh3 + C_ * C_;
        mfma_gemm64<false>((const ushort_t(*)[136])xlnb,
                           (const ushort_t(*)[136])xlnb, Bh3, Bl3, lane, n0, ao);
    }
    {
        #pragma unroll
        for (int n = 0; n < 2; ++n) {
            const int col = n0 + (n << 4) + ar;
            const float bpv = bp[col];
            #pragma unroll
            for (int m = 0; m < 4; ++m)
                #pragma unroll
                for (int r = 0; r < 4; ++r) {
                    const int row = (m << 4) + rg + r;
                    out[(size_t)(tok0 + row) * C_ + col] = ao[m][n][r] + bpv;
                }
        }
    }
}

// ---------------------------------------------------------------------------
extern "C" void kernel_launch(void* const* d_in, const int* in_sizes, int n_in,
                              void* d_out, int out_size, void* d_ws, size_t ws_size,
                              hipStream_t stream) {
    const float* x     = (const float*)d_in[0];
    const float* Wf    = (const float*)d_in[1];
    const float* bf    = (const float*)d_in[2];
    const float* Wh    = (const float*)d_in[3];
    const float* bh    = (const float*)d_in[4];
    const float* gamma = (const float*)d_in[5];
    const float* beta  = (const float*)d_in[6];
    const float* Wp    = (const float*)d_in[7];
    const float* bp    = (const float*)d_in[8];
    const float* k0    = (const float*)d_in[9];
    const float* k1    = (const float*)d_in[10];
    const float* k2    = (const float*)d_in[11];
    float* out = (float*)d_out;

    const size_t NC = (size_t)NTOK * C_;
    ushort_t* P0  = (ushort_t*)d_ws;          // ctx transposed
    ushort_t* ACC = P0 + NC;                  // ctx_all (token-major)
    float* gates  = (float*)(ACC + NC);
    float* csum   = gates + (size_t)NTOK * 4;
    float* whc    = csum + (size_t)B_ * C_;
    ushort_t* pkw = (ushort_t*)(whc + (size_t)B_ * C_);  // 4x(2x128x128) + 2x16x128 bf16

    pack_weights<<<dim3(C_, 5), 128, 0, stream>>>(Wf, Wh, Wp, pkw);
    gemm_ctx_gates_mfma<<<NTOK / 64, 256, 0, stream>>>(x, bf, pkw, P0, gates, csum);
    focal_conv_fused<<<dim3(C_/8, (H_/TH)*(W_/TW), B_), 256, 0, stream>>>(
        P0, k0, k1, k2, gates, ACC, csum);
    glob_mod<<<B_, 128, 0, stream>>>(csum, Wh, whc);
    modq_ln_out_mfma<<<NTOK / 64, 256, 0, stream>>>(
        ACC, whc, gates, x, pkw, bf, bh, gamma, beta, bp, out);
}

// Round 6
// 405.714 us; speedup vs baseline: 1.1167x; 1.0552x over previous
//
#include <hip/hip_runtime.h>
#include <math.h>

#define B_ 16
#define H_ 96
#define W_ 96
#define C_ 128
#define HW_ (H_*W_)            // 9216
#define NTOK (B_*HW_)          // 147456
#define NOUT 260

// fused conv tile geometry
#define TH 16
#define TW 32
#define B0H 28
#define B0W 44
#define B1H 26
#define B1W 42
#define B2H 22
#define B2W 38

typedef unsigned short ushort_t;
typedef unsigned int uint_t;
typedef float f32x4 __attribute__((ext_vector_type(4)));
typedef float f32x2 __attribute__((ext_vector_type(2)));
typedef short bfrag __attribute__((ext_vector_type(8)));    // 8 bf16 = 4 VGPRs (MFMA A/B frag)
typedef unsigned short us8 __attribute__((ext_vector_type(8)));

// OCML erff-based gelu — measured fastest (R3: 171 us vs R5 rational: 178.5)
__device__ __forceinline__ float gelu_f(float t) {
    return 0.5f * t * (1.0f + erff(t * 0.7071067811865475f));
}
__device__ __forceinline__ float b2f(ushort_t u) {
    union { unsigned int i; float f; } t; t.i = (unsigned int)u << 16; return t.f;
}
__device__ __forceinline__ ushort_t f2b(float f) {
    union { float f; unsigned int i; } t; t.f = f;
    unsigned int lsb = (t.i >> 16) & 1u;
    t.i += 0x7fffu + lsb;            // round-to-nearest-even
    return (ushort_t)(t.i >> 16);
}
// HW packed fp32->bf16 RNE convert: ONE v_cvt_pk_bf16_f32 (a->low16, b->high16)
// replaces ~11 ops of bit-math RNE. (gfx950; verified in guide T12.)
__device__ __forceinline__ uint_t pk2(float a, float b) {
    uint_t r;
    asm("v_cvt_pk_bf16_f32 %0, %1, %2" : "=v"(r) : "v"(a), "v"(b));
    return r;
}
__device__ __forceinline__ void unp2(uint_t u, float& a, float& b) {
    union { unsigned int i; float f; } x, y;
    x.i = u << 16; y.i = u & 0xffff0000u;
    a = x.f; b = y.f;
}
__device__ __forceinline__ void unp8(const uint4 v, float* f) {
    unp2(v.x, f[0], f[1]); unp2(v.y, f[2], f[3]);
    unp2(v.z, f[4], f[5]); unp2(v.w, f[6], f[7]);
}
__device__ __forceinline__ uint4 pk8(const float* f) {
    uint4 v;
    v.x = pk2(f[0], f[1]); v.y = pk2(f[2], f[3]);
    v.z = pk2(f[4], f[5]); v.w = pk2(f[6], f[7]);
    return v;
}
// packed (float2) unpack of 8 bf16 channels
__device__ __forceinline__ f32x2 unp2p(uint_t u) {
    union { uint_t i; float f; } a, b;
    a.i = u << 16; b.i = u & 0xffff0000u;
    f32x2 r; r.x = a.f; r.y = b.f; return r;
}
__device__ __forceinline__ void unp8p(const uint4 v, f32x2* d) {
    d[0] = unp2p(v.x); d[1] = unp2p(v.y); d[2] = unp2p(v.z); d[3] = unp2p(v.w);
}

// split fp32 -> bf16 hi/lo (Markidis) via cvt_pk: 6 ops/pair vs ~22.
// hi = RNE(f) (identical to old f2b); lo = RNE(f - hi). Bit-identical results.
__device__ __forceinline__ void split8_to(const float* f,
                                          ushort_t* __restrict__ hdst,
                                          ushort_t* __restrict__ ldst) {
    uint_t hp[4], lp[4];
    #pragma unroll
    for (int j = 0; j < 4; ++j) {
        const float a = f[2*j], b = f[2*j+1];
        const uint_t h = pk2(a, b);
        union { uint_t i; float f; } ha, hb;
        ha.i = h << 16; hb.i = h & 0xffff0000u;
        hp[j] = h;
        lp[j] = pk2(a - ha.f, b - hb.f);
    }
    *(uint4*)hdst = make_uint4(hp[0], hp[1], hp[2], hp[3]);
    *(uint4*)ldst = make_uint4(lp[0], lp[1], lp[2], lp[3]);
}

// ---------------------------------------------------------------------------
// K0: pack weights into MFMA-B-fragment-native layout, transposed + split.
// pk layout: [mat][hi=0/lo=1][n][k(128)] bf16;
// mat 0 = Wf[:,0:128] (q), 1 = Wf[:,128:256] (ctx), 2 = Wh, 3 = Wp (n=128 each)
// mat 4 = Wf[:,256:260] gate cols padded to n=16 (cols 4..15 zero)
// ---------------------------------------------------------------------------
__global__ __launch_bounds__(128) void pack_weights(
    const float* __restrict__ Wf, const float* __restrict__ Wh,
    const float* __restrict__ Wp, ushort_t* __restrict__ pk)
{
    const int n = blockIdx.x, mat = blockIdx.y, k = threadIdx.x;
    if (mat == 4 && n >= 16) return;
    float v;
    if (mat == 0)      v = Wf[(size_t)k * NOUT + n];
    else if (mat == 1) v = Wf[(size_t)k * NOUT + C_ + n];
    else if (mat == 2) v = Wh[(size_t)k * C_ + n];
    else if (mat == 3) v = Wp[(size_t)k * C_ + n];
    else               v = (n < 4) ? Wf[(size_t)k * NOUT + 2*C_ + n] : 0.0f;
    const ushort_t h = f2b(v);
    const ushort_t l = f2b(v - b2f(h));
    ushort_t* base = pk + (size_t)mat * (2 * C_ * C_);
    const int lo_off = (mat == 4) ? 16 * C_ : C_ * C_;
    base[n * C_ + k] = h;
    base[lo_off + n * C_ + k] = l;
}

// ---------------------------------------------------------------------------
// Per-wave split-bf16 GEMM: 64(tokens) x 32(cols at n0) x K=128.
// acc layout: acc[m][n], D row = m*16 + (lane>>4)*4 + reg, col = n0+n*16+(lane&15)
// ---------------------------------------------------------------------------
template <bool A_LO>
__device__ __forceinline__ void mfma_gemm64(
    const ushort_t (*Ah)[136], const ushort_t (*Al)[136],
    const ushort_t* __restrict__ Bh, const ushort_t* __restrict__ Bl,
    int lane, int n0, f32x4 acc[4][2])
{
    const int ar = lane & 15;               // A row / B col within tile
    const int ak = (lane >> 4) << 3;        // k offset within 32-step
    #pragma unroll
    for (int kk = 0; kk < 4; ++kk) {
        const int kb = (kk << 5) + ak;
        const bfrag bh0 = *(const bfrag*)(Bh + (((n0      + ar) << 7) + kb));
        const bfrag bh1 = *(const bfrag*)(Bh + (((n0 + 16 + ar) << 7) + kb));
        const bfrag bl0 = *(const bfrag*)(Bl + (((n0      + ar) << 7) + kb));
        const bfrag bl1 = *(const bfrag*)(Bl + (((n0 + 16 + ar) << 7) + kb));
        #pragma unroll
        for (int m = 0; m < 4; ++m) {
            const bfrag ah = *(const bfrag*)&Ah[(m << 4) + ar][kb];
            if constexpr (A_LO) {
                const bfrag al = *(const bfrag*)&Al[(m << 4) + ar][kb];
                acc[m][0] = __builtin_amdgcn_mfma_f32_16x16x32_bf16(al, bh0, acc[m][0], 0, 0, 0);
                acc[m][1] = __builtin_amdgcn_mfma_f32_16x16x32_bf16(al, bh1, acc[m][1], 0, 0, 0);
            }
            acc[m][0] = __builtin_amdgcn_mfma_f32_16x16x32_bf16(ah, bl0, acc[m][0], 0, 0, 0);
            acc[m][1] = __builtin_amdgcn_mfma_f32_16x16x32_bf16(ah, bl1, acc[m][1], 0, 0, 0);
            acc[m][0] = __builtin_amdgcn_mfma_f32_16x16x32_bf16(ah, bh0, acc[m][0], 0, 0, 0);
            acc[m][1] = __builtin_amdgcn_mfma_f32_16x16x32_bf16(ah, bh1, acc[m][1], 0, 0, 0);
        }
    }
}

// stage 64x128 fp32 tile -> LDS bf16 hi/lo (coalesced 32B/thread reads)
__device__ __forceinline__ void stage_split_f32(
    const float* __restrict__ src, int tid,
    ushort_t (*Ah)[136], ushort_t (*Al)[136])
{
    #pragma unroll
    for (int p = 0; p < 4; ++p) {
        const int i  = tid + (p << 8);        // 0..1023
        const int t  = i >> 4;                // token row
        const int c8 = (i & 15) << 3;         // k chunk
        const float4 v0 = *(const float4*)(src + (size_t)t * C_ + c8);
        const float4 v1 = *(const float4*)(src + (size_t)t * C_ + c8 + 4);
        const float f[8] = {v0.x, v0.y, v0.z, v0.w, v1.x, v1.y, v1.z, v1.w};
        split8_to(f, &Ah[t][c8], &Al[t][c8]);
    }
}

// ---------------------------------------------------------------------------
// K1: ctx = (x @ Wf)[:, 128:256] + bf ; gates = (x @ Wf)[:, 256:260] + bf
// gates via padded 16-col MFMA tile (mat 4), one tile per wave.
// ---------------------------------------------------------------------------
__global__ __launch_bounds__(256) void gemm_ctx_gates_mfma(
    const float* __restrict__ x, const float* __restrict__ bf,
    const ushort_t* __restrict__ pk,
    ushort_t* __restrict__ ctx, float* __restrict__ gates,
    float* __restrict__ csum)
{
    __shared__ ushort_t Abuf[2][64][136];     // hi / lo (34816 B)
    const int tid  = threadIdx.x;
    const int tok0 = blockIdx.x * 64;
    const int lane = tid & 63;
    const int n0   = (tid >> 6) << 5;         // wave's 32-col strip

    if (blockIdx.x < 8) csum[blockIdx.x * 256 + tid] = 0.0f;

    stage_split_f32(x + (size_t)tok0 * C_, tid, Abuf[0], Abuf[1]);
    __syncthreads();

    f32x4 acc[4][2] = {};
    {
        const ushort_t* Bh = pk + (size_t)1 * (2 * C_ * C_);   // mat 1 = Wf ctx cols
        const ushort_t* Bl = Bh + C_ * C_;
        mfma_gemm64<true>(Abuf[0], Abuf[1], Bh, Bl, lane, n0, acc);
    }

    // gates: wave w computes its own 16-row tile against the padded gate cols
    {
        const int w  = tid >> 6;
        const int ar = lane & 15;
        const int ak = (lane >> 4) << 3;
        const ushort_t* Gh = pk + (size_t)4 * (2 * C_ * C_);
        const ushort_t* Gl = Gh + 16 * C_;
        f32x4 gacc = {};
        #pragma unroll
        for (int kk = 0; kk < 4; ++kk) {
            const int kb = (kk << 5) + ak;
            const bfrag gh = *(const bfrag*)(Gh + ((ar << 7) + kb));
            const bfrag gl = *(const bfrag*)(Gl + ((ar << 7) + kb));
            const bfrag ah = *(const bfrag*)&Abuf[0][(w << 4) + ar][kb];
            const bfrag al = *(const bfrag*)&Abuf[1][(w << 4) + ar][kb];
            gacc = __builtin_amdgcn_mfma_f32_16x16x32_bf16(al, gh, gacc, 0, 0, 0);
            gacc = __builtin_amdgcn_mfma_f32_16x16x32_bf16(ah, gl, gacc, 0, 0, 0);
            gacc = __builtin_amdgcn_mfma_f32_16x16x32_bf16(ah, gh, gacc, 0, 0, 0);
        }
        if (ar < 4) {
            const int rg = (lane >> 4) << 2;
            #pragma unroll
            for (int r = 0; r < 4; ++r)
                gates[(size_t)(tok0 + (w << 4) + rg + r) * 4 + ar] = gacc[r] + bf[2*C_ + ar];
        }
    }
    __syncthreads();   // all LDS reads done before overwrite

    // epilogue: acc + bias -> bf16 via cvt_pk pairs -> Abuf[0] as ctx_lds[64][136]
    {
        const int ar = lane & 15;
        const int rg = (lane >> 4) << 2;
        #pragma unroll
        for (int n = 0; n < 2; ++n) {
            const int col = n0 + (n << 4) + ar;
            const float bias = bf[C_ + col];
            #pragma unroll
            for (int m = 0; m < 4; ++m) {
                const int rowb = (m << 4) + rg;
                const uint_t p0 = pk2(acc[m][n][0] + bias, acc[m][n][1] + bias);
                const uint_t p1 = pk2(acc[m][n][2] + bias, acc[m][n][3] + bias);
                Abuf[0][rowb + 0][col] = (ushort_t)p0;
                Abuf[0][rowb + 1][col] = (ushort_t)(p0 >> 16);
                Abuf[0][rowb + 2][col] = (ushort_t)p1;
                Abuf[0][rowb + 3][col] = (ushort_t)(p1 >> 16);
            }
        }
    }
    __syncthreads();

    // coalesced transposed store: ctx[colgrp][token][8]
    #pragma unroll
    for (int p = 0; p < 4; ++p) {
        const int i  = tid + (p << 8);
        const int cg = i >> 6;
        const int t  = i & 63;
        *(uint4*)(ctx + (((size_t)cg * NTOK + tok0 + t) << 3))
            = *(const uint4*)&Abuf[0][t][cg << 3];
    }
}

// ---------------------------------------------------------------------------
// K2 (fused): conv3->gelu->conv5->gelu->conv7->gelu cascade in LDS.
// (proven structure; packed f32x2 FMA; erff gelu; cvt_pk bf16 stores)
// ---------------------------------------------------------------------------
__global__ __launch_bounds__(256, 4) void focal_conv_fused(
    const ushort_t* __restrict__ ctx_in,
    const float* __restrict__ k0w, const float* __restrict__ k1w,
    const float* __restrict__ k2w,
    const float* __restrict__ gates,
    ushort_t* __restrict__ ctx_all,
    float* __restrict__ csum)
{
    __shared__ uint4 bufA[B0H*B0W];            // 19712 B (stage0 in; stage2 out 22x38)
    __shared__ uint4 buf1[B1H*B1W];            // 17472 B
    __shared__ float wts[(9+25+49)*8];         //  2656 B   (39840 total)

    const int tid  = threadIdx.x;
    const int cg   = blockIdx.x;               // 0..15 channel group
    const int tile = blockIdx.y;               // 0..17
    const int bb   = blockIdx.z;               // 0..15
    const int wt   = tile % 3, ht = tile / 3;
    const int c0   = cg << 3;
    const int h0   = ht * TH, w0 = wt * TW;

    // weights -> LDS (83 taps x 8 ch)
    if (tid < 166) {
        const int f = tid << 2;
        const float* src; int r;
        if (f < 72)       { r = f;       src = k0w; }
        else if (f < 272) { r = f - 72;  src = k1w; }
        else              { r = f - 272; src = k2w; }
        const int tap = r >> 3, off = r & 7;
        *(float4*)&wts[f] = *(const float4*)(src + tap * C_ + c0 + off);
    }

    // stage 0: global -> bufA (contiguous reads from transposed ctx)
    const ushort_t* cin = ctx_in + (((size_t)cg * NTOK + (size_t)bb * HW_) << 3);
    for (int i = tid; i < B0H*B0W; i += 256) {
        const int r = i / B0W, q = i - r * B0W;
        const int hh = h0 - 6 + r, ww = w0 - 6 + q;
        uint4 v = make_uint4(0u, 0u, 0u, 0u);
        if ((unsigned)hh < (unsigned)H_ && (unsigned)ww < (unsigned)W_)
            v = *(const uint4*)(cin + ((size_t)(hh * W_ + ww) << 3));
        bufA[i] = v;
    }
    __syncthreads();

    // ---- stage 1: buf1 = gelu(conv3(bufA))  [26x42] ----
    {
        int iv[5], ecp[5], boff[5];
        #pragma unroll
        for (int p = 0; p < 5; ++p) {
            const int e = tid + (p << 8);
            iv[p] = (e < B1H*B1W);
            const int ec = iv[p] ? e : 0;
            ecp[p] = ec;
            boff[p] = (ec / B1W) * B0W + (ec % B1W);
        }
        f32x2 acc[5][4] = {};
        #pragma unroll 1
        for (int a = 0; a < 3; ++a) {
            #pragma unroll
            for (int b = 0; b < 3; ++b) {
                f32x2 wv[4];
                #pragma unroll
                for (int c = 0; c < 4; ++c)
                    wv[c] = *(const f32x2*)&wts[(a*3+b)*8 + 2*c];
                const int off = a * B0W + b;
                #pragma unroll
                for (int p = 0; p < 5; ++p) {
                    f32x2 d[4]; unp8p(bufA[boff[p] + off], d);
                    #pragma unroll
                    for (int c = 0; c < 4; ++c)
                        acc[p][c] = __builtin_elementwise_fma(d[c], wv[c], acc[p][c]);
                }
            }
        }
        __syncthreads();   // all bufA reads done before stage2 overwrites it
        #pragma unroll
        for (int p = 0; p < 5; ++p) if (iv[p]) {
            float g[8];
            #pragma unroll
            for (int c = 0; c < 4; ++c) {
                g[2*c]   = gelu_f(acc[p][c].x);
                g[2*c+1] = gelu_f(acc[p][c].y);
            }
            buf1[ecp[p]] = pk8(g);
        }
    }
    __syncthreads();

    // ---- stage 2: bufA = gelu(conv5(buf1))  [22x38] ----
    {
        int iv[4], ecp[4], boff[4];
        #pragma unroll
        for (int p = 0; p < 4; ++p) {
            const int e = tid + (p << 8);
            iv[p] = (e < B2H*B2W);
            const int ec = iv[p] ? e : 0;
            ecp[p] = ec;
            boff[p] = (ec / B2W) * B1W + (ec % B2W);
        }
        f32x2 acc[4][4] = {};
        #pragma unroll 1
        for (int a = 0; a < 5; ++a) {
            #pragma unroll
            for (int b = 0; b < 5; ++b) {
                f32x2 wv[4];
                #pragma unroll
                for (int c = 0; c < 4; ++c)
                    wv[c] = *(const f32x2*)&wts[72 + (a*5+b)*8 + 2*c];
                const int off = a * B1W + b;
                #pragma unroll
                for (int p = 0; p < 4; ++p) {
                    f32x2 d[4]; unp8p(buf1[boff[p] + off], d);
                    #pragma unroll
                    for (int c = 0; c < 4; ++c)
                        acc[p][c] = __builtin_elementwise_fma(d[c], wv[c], acc[p][c]);
                }
            }
        }
        __syncthreads();   // bufA stage-0 data fully dead — safe to overwrite
        #pragma unroll
        for (int p = 0; p < 4; ++p) if (iv[p]) {
            float g[8];
            #pragma unroll
            for (int c = 0; c < 4; ++c) {
                g[2*c]   = gelu_f(acc[p][c].x);
                g[2*c+1] = gelu_f(acc[p][c].y);
            }
            bufA[ecp[p]] = pk8(g);
        }
    }
    __syncthreads();

    // ---- stage 3: ctx3 = gelu(conv7(bufA)); combine 3 gated levels ----
    float lsum[8] = {};
    {
        const int th0 = tid >> 5, tw0 = tid & 31;   // p adds 8 to th
        f32x2 acc[2][4] = {};
        #pragma unroll 1
        for (int a = 0; a < 7; ++a) {
            #pragma unroll
            for (int b = 0; b < 7; ++b) {
                f32x2 wv[4];
                #pragma unroll
                for (int c = 0; c < 4; ++c)
                    wv[c] = *(const f32x2*)&wts[272 + (a*7+b)*8 + 2*c];
                #pragma unroll
                for (int p = 0; p < 2; ++p) {
                    const int th = th0 + (p << 3);
                    f32x2 d[4]; unp8p(bufA[(th + a)*B2W + (tw0 + b)], d);
                    #pragma unroll
                    for (int c = 0; c < 4; ++c)
                        acc[p][c] = __builtin_elementwise_fma(d[c], wv[c], acc[p][c]);
                }
            }
        }
        #pragma unroll
        for (int p = 0; p < 2; ++p) {
            const int th = th0 + (p << 3);
            float ctx3[8];
            #pragma unroll
            for (int c = 0; c < 4; ++c) {
                ctx3[2*c]   = gelu_f(acc[p][c].x);
                ctx3[2*c+1] = gelu_f(acc[p][c].y);
            }
            #pragma unroll
            for (int c = 0; c < 8; ++c) lsum[c] += ctx3[c];
            float d1[8]; unp8(buf1[(5+th)*B1W + (5+tw0)], d1);
            float d2[8]; unp8(bufA[(th+3)*B2W + (tw0+3)], d2);
            const size_t pix = (size_t)bb * HW_ + (size_t)(h0 + th) * W_ + (w0 + tw0);
            const float4 gt = *(const float4*)(gates + pix * 4);
            float o[8];
            #pragma unroll
            for (int c = 0; c < 8; ++c)
                o[c] = d1[c] * gt.x + d2[c] * gt.y + ctx3[c] * gt.z;
            *(uint4*)(ctx_all + pix * C_ + c0) = pk8(o);
        }
    }

    // per-block channel sums of final ctx -> atomic accumulate
    __syncthreads();
    float* red = (float*)bufA;
    #pragma unroll
    for (int c = 0; c < 8; ++c) red[c*256 + tid] = lsum[c];
    __syncthreads();
    for (int off = 128; off > 0; off >>= 1) {
        if (tid < off) {
            #pragma unroll
            for (int c = 0; c < 8; ++c)
                red[c*256 + tid] += red[c*256 + tid + off];
        }
        __syncthreads();
    }
    if (tid < 8) atomicAdd(&csum[bb * C_ + c0 + tid], red[tid * 256]);
}

// ---------------------------------------------------------------------------
// K3: whc[b][n] = sum_k gelu(csum[b][k]/HW) * Wh[k][n]   (rank-1 factor of the
// global-context modulator)
// ---------------------------------------------------------------------------
__global__ __launch_bounds__(128) void glob_mod(
    const float* __restrict__ csum, const float* __restrict__ Wh,
    float* __restrict__ whc)
{
    __shared__ float cg[128];
    const int b = blockIdx.x, n = threadIdx.x;
    cg[n] = gelu_f(csum[b * C_ + n] * (1.0f / (float)HW_));
    __syncthreads();
    float s = 0.f;
    #pragma unroll 8
    for (int k = 0; k < C_; ++k)
        s = fmaf(cg[k], Wh[(size_t)k * C_ + n], s);
    whc[b * C_ + n] = s;
}

// ---------------------------------------------------------------------------
// K4 (fused): mod = ctx_all@Wh + g3*whc + bh ; q = x@Wf[:,:C] + bf[:C] ;
// x_out = q*mod ; LayerNorm ; out = xln@Wp + bp   — all in one block pass.
// ---------------------------------------------------------------------------
__global__ __launch_bounds__(256) void modq_ln_out_mfma(
    const ushort_t* __restrict__ ctx_all, const float* __restrict__ whc,
    const float* __restrict__ gates, const float* __restrict__ x,
    const ushort_t* __restrict__ pk, const float* __restrict__ bf,
    const float* __restrict__ bh, const float* __restrict__ gamma,
    const float* __restrict__ beta, const float* __restrict__ bp,
    float* __restrict__ out)
{
    __shared__ ushort_t Abuf[2][64][136];     // hi/lo staging; later aliased as xs/xln
    __shared__ float g3s[64];
    __shared__ float whcs[128];
    __shared__ float mu_s[64];
    __shared__ float rs_s[64];
    __shared__ f32x2 part[64][4];             // LN partial (s, s2) per quarter-row
    float (*xs)[132] = (float(*)[132])&Abuf[0][0][0];       // 33792 B <= 34816 B
    ushort_t (*xlnb)[136] = (ushort_t(*)[136])&Abuf[0][0][0];

    const int tid  = threadIdx.x;
    const int tok0 = blockIdx.x * 64;
    const int bidx = tok0 / HW_;
    const int lane = tid & 63;
    const int n0   = (tid >> 6) << 5;
    const int ar   = lane & 15;
    const int rg   = (lane >> 4) << 2;

    // ---- stage ctx_all (bf16, no split) + g3/whc row caches ----
    #pragma unroll
    for (int p = 0; p < 4; ++p) {
        const int i  = tid + (p << 8);
        const int t  = i >> 4;
        const int c8 = (i & 15) << 3;
        *(us8*)&Abuf[0][t][c8] = *(const us8*)(ctx_all + (size_t)(tok0 + t) * C_ + c8);
    }
    if (tid < 64)           g3s[tid]        = gates[(size_t)(tok0 + tid) * 4 + 3];
    else if (tid < 192)     whcs[tid - 64]  = whc[bidx * C_ + (tid - 64)];
    __syncthreads();

    f32x4 am[4][2] = {};
    {
        const ushort_t* Bh2 = pk + (size_t)2 * (2 * C_ * C_);   // mat 2 = Wh
        const ushort_t* Bl2 = Bh2 + C_ * C_;
        mfma_gemm64<false>(Abuf[0], Abuf[0], Bh2, Bl2, lane, n0, am);
    }
    __syncthreads();   // all mod-frag reads done before restaging

    // ---- stage A_q = x, split hi/lo ----
    stage_split_f32(x + (size_t)tok0 * C_, tid, Abuf[0], Abuf[1]);
    __syncthreads();

    f32x4 aq[4][2] = {};
    {
        const ushort_t* Bh0 = pk;                                // mat 0 = Wf q cols
        const ushort_t* Bl0 = Bh0 + C_ * C_;
        mfma_gemm64<true>(Abuf[0], Abuf[1], Bh0, Bl0, lane, n0, aq);
    }
    __syncthreads();   // all q-frag reads done before xs overwrites LDS

    // ---- x_out = (q + bf) * (mod + g3*whc + bh) -> xs ----
    {
        #pragma unroll
        for (int n = 0; n < 2; ++n) {
            const int col = n0 + (n << 4) + ar;
            const float bfv = bf[col];
            const float bhv = bh[col];
            const float whv = whcs[col];
            #pragma unroll
            for (int m = 0; m < 4; ++m)
                #pragma unroll
                for (int r = 0; r < 4; ++r) {
                    const int row = (m << 4) + rg + r;
                    const float mod = am[m][n][r] + g3s[row] * whv + bhv;
                    xs[row][col] = (aq[m][n][r] + bfv) * mod;
                }
        }
    }
    __syncthreads();

    // ---- LN stats: all 256 threads, quarter-row partials ----
    {
        const int tt = tid >> 2;
        const int qq = tid & 3;
        float s = 0.f, s2 = 0.f;
        #pragma unroll
        for (int c = 0; c < 32; c += 4) {
            const float4 v = *(const float4*)&xs[tt][(qq << 5) + c];
            s  += v.x + v.y + v.z + v.w;
            s2 += v.x*v.x + v.y*v.y + v.z*v.z + v.w*v.w;
        }
        f32x2 pr; pr.x = s; pr.y = s2;
        part[tt][qq] = pr;
    }
    __syncthreads();
    if (tid < 64) {
        const f32x2 p0 = part[tid][0], p1 = part[tid][1];
        const f32x2 p2 = part[tid][2], p3 = part[tid][3];
        const float s  = (p0.x + p1.x) + (p2.x + p3.x);
        const float s2 = (p0.y + p1.y) + (p2.y + p3.y);
        const float mu  = s * (1.0f / 128.0f);
        const float var = s2 * (1.0f / 128.0f) - mu * mu;
        mu_s[tid] = mu;
        rs_s[tid] = rsqrtf(var + 0.001f);
    }
    __syncthreads();

    // ---- LN apply into registers (xs still live), then write xln bf16 ----
    {
        const int tt = tid >> 2;
        const int c0b = (tid & 3) << 5;
        const float mu = mu_s[tt], rs = rs_s[tt];
        uint_t xw[16];
        #pragma unroll
        for (int j = 0; j < 8; ++j) {
            const int c = c0b + (j << 2);
            const float4 v  = *(const float4*)&xs[tt][c];
            const float4 gm = *(const float4*)(gamma + c);
            const float4 bt = *(const float4*)(beta + c);
            xw[2*j]   = pk2((v.x - mu) * rs * gm.x + bt.x,
                            (v.y - mu) * rs * gm.y + bt.y);
            xw[2*j+1] = pk2((v.z - mu) * rs * gm.z + bt.z,
                            (v.w - mu) * rs * gm.w + bt.w);
        }
        __syncthreads();   // all xs reads complete before overwrite
        #pragma unroll
        for (int j = 0; j < 4; ++j)
            *(uint4*)&xlnb[tt][c0b + (j << 3)] = *(uint4*)&xw[4*j];
    }
    __syncthreads();

    // ---- out = xln @ Wp + bp ----
    f32x4 ao[4][2] = {};
    {
        const ushort_t* Bh3 = pk + (size_t)3 * (2 * C_ * C_);   // mat 3 = Wp
        const ushort_t* Bl3 = Bh3 + C_ * C_;
        mfma_gemm64<false>((const ushort_t(*)[136])xlnb,
                           (const ushort_t(*)[136])xlnb, Bh3, Bl3, lane, n0, ao);
    }
    {
        #pragma unroll
        for (int n = 0; n < 2; ++n) {
            const int col = n0 + (n << 4) + ar;
            const float bpv = bp[col];
            #pragma unroll
            for (int m = 0; m < 4; ++m)
                #pragma unroll
                for (int r = 0; r < 4; ++r) {
                    const int row = (m << 4) + rg + r;
                    out[(size_t)(tok0 + row) * C_ + col] = ao[m][n][r] + bpv;
                }
        }
    }
}

// ---------------------------------------------------------------------------
extern "C" void kernel_launch(void* const* d_in, const int* in_sizes, int n_in,
                              void* d_out, int out_size, void* d_ws, size_t ws_size,
                              hipStream_t stream) {
    const float* x     = (const float*)d_in[0];
    const float* Wf    = (const float*)d_in[1];
    const float* bf    = (const float*)d_in[2];
    const float* Wh    = (const float*)d_in[3];
    const float* bh    = (const float*)d_in[4];
    const float* gamma = (const float*)d_in[5];
    const float* beta  = (const float*)d_in[6];
    const float* Wp    = (const float*)d_in[7];
    const float* bp    = (const float*)d_in[8];
    const float* k0    = (const float*)d_in[9];
    const float* k1    = (const float*)d_in[10];
    const float* k2    = (const float*)d_in[11];
    float* out = (float*)d_out;

    const size_t NC = (size_t)NTOK * C_;
    ushort_t* P0  = (ushort_t*)d_ws;          // ctx transposed
    ushort_t* ACC = P0 + NC;                  // ctx_all (token-major)
    float* gates  = (float*)(ACC + NC);
    float* csum   = gates + (size_t)NTOK * 4;
    float* whc    = csum + (size_t)B_ * C_;
    ushort_t* pkw = (ushort_t*)(whc + (size_t)B_ * C_);  // 4x(2x128x128) + 2x16x128 bf16

    pack_weights<<<dim3(C_, 5), 128, 0, stream>>>(Wf, Wh, Wp, pkw);
    gemm_ctx_gates_mfma<<<NTOK / 64, 256, 0, stream>>>(x, bf, pkw, P0, gates, csum);
    focal_conv_fused<<<dim3(C_/8, (H_/TH)*(W_/TW), B_), 256, 0, stream>>>(
        P0, k0, k1, k2, gates, ACC, csum);
    glob_mod<<<B_, 128, 0, stream>>>(csum, Wh, whc);
    modq_ln_out_mfma<<<NTOK / 64, 256, 0, stream>>>(
        ACC, whc, gates, x, pkw, bf, bh, gamma, beta, bp, out);
}

// Round 8
// 381.929 us; speedup vs baseline: 1.1862x; 1.0623x over previous
//
#include <hip/hip_runtime.h>
#include <math.h>

#define B_ 16
#define H_ 96
#define W_ 96
#define C_ 128
#define HW_ (H_*W_)            // 9216
#define NTOK (B_*HW_)          // 147456
#define NOUT 260

// fused conv tile geometry
#define TH 16
#define TW 32
#define B0H 28
#define B0W 44
#define B1H 26
#define B1W 42
#define B2H 22
#define B2W 38

typedef unsigned short ushort_t;
typedef unsigned int uint_t;
typedef float f32x4 __attribute__((ext_vector_type(4)));
typedef float f32x2 __attribute__((ext_vector_type(2)));
typedef __fp16 fp16x2 __attribute__((ext_vector_type(2)));    // cvt_pkrtz result type
typedef _Float16 h16x8 __attribute__((ext_vector_type(8)));   // MFMA f16 A/B frag (4 VGPRs)
typedef unsigned short us8 __attribute__((ext_vector_type(8)));

// OCML erff-based gelu — measured fastest (R3/R5/R6 A/B)
__device__ __forceinline__ float gelu_f(float t) {
    return 0.5f * t * (1.0f + erff(t * 0.7071067811865475f));
}

// packed fp32->f16 convert (RTZ): ONE v_cvt_pkrtz_f16_f32
__device__ __forceinline__ uint_t pkh2(float a, float b) {
    union { fp16x2 h; uint_t u; } c;
    c.h = __builtin_amdgcn_cvt_pkrtz(a, b);
    return c.u;
}
__device__ __forceinline__ uint4 pkh8(const float* f) {
    uint4 v;
    v.x = pkh2(f[0], f[1]); v.y = pkh2(f[2], f[3]);
    v.z = pkh2(f[4], f[5]); v.w = pkh2(f[6], f[7]);
    return v;
}
// f16 pair -> two f32 (2x v_cvt_f32_f16)
__device__ __forceinline__ void unph2(uint_t u, float& a, float& b) {
    union { uint_t u; _Float16 h[2]; } c; c.u = u;
    a = (float)c.h[0]; b = (float)c.h[1];
}
__device__ __forceinline__ void unph8(const uint4 v, float* f) {
    unph2(v.x, f[0], f[1]); unph2(v.y, f[2], f[3]);
    unph2(v.z, f[4], f[5]); unph2(v.w, f[6], f[7]);
}

// mixed-precision FMA: f32 acc += f16(lo/hi of d) * f16(lo/hi of w).
// v_fma_mix_f32 reads f16 halves directly — no unpack ALU.
__device__ __forceinline__ void fmix2(float& a0, float& a1, uint_t d, uint_t w) {
    asm("v_fma_mix_f32 %0, %2, %3, %0 op_sel_hi:[1,1,0]\n\t"
        "v_fma_mix_f32 %1, %2, %3, %1 op_sel:[1,1,0] op_sel_hi:[1,1,0]"
        : "+v"(a0), "+v"(a1) : "v"(d), "v"(w));
}
__device__ __forceinline__ void fmix8(float* acc, const uint4 d, const uint4 w) {
    fmix2(acc[0], acc[1], d.x, w.x);
    fmix2(acc[2], acc[3], d.y, w.y);
    fmix2(acc[4], acc[5], d.z, w.z);
    fmix2(acc[6], acc[7], d.w, w.w);
}

// split fp32 -> f16 hi/lo: a ~= hi + lo (hi RTZ; lo captures residual -> ~2^-21)
__device__ __forceinline__ void split8_to(const float* f,
                                          ushort_t* __restrict__ hdst,
                                          ushort_t* __restrict__ ldst) {
    uint_t hp[4], lp[4];
    #pragma unroll
    for (int j = 0; j < 4; ++j) {
        const float a = f[2*j], b = f[2*j+1];
        const uint_t h = pkh2(a, b);
        float ha, hb; unph2(h, ha, hb);
        hp[j] = h;
        lp[j] = pkh2(a - ha, b - hb);
    }
    *(uint4*)hdst = make_uint4(hp[0], hp[1], hp[2], hp[3]);
    *(uint4*)ldst = make_uint4(lp[0], lp[1], lp[2], lp[3]);
}

// ---------------------------------------------------------------------------
// K0: pack weights into MFMA-B-fragment-native layout, transposed + f16 split.
// pk layout: [mat][hi=0/lo=1][n][k(128)] f16;
// mat 0 = Wf[:,0:128] (q), 1 = Wf[:,128:256] (ctx), 2 = Wh, 3 = Wp (n=128 each)
// mat 4 = Wf[:,256:260] gate cols padded to n=16 (cols 4..15 zero)
// ---------------------------------------------------------------------------
__global__ __launch_bounds__(128) void pack_weights(
    const float* __restrict__ Wf, const float* __restrict__ Wh,
    const float* __restrict__ Wp, ushort_t* __restrict__ pk)
{
    const int n = blockIdx.x, mat = blockIdx.y, k = threadIdx.x;
    if (mat == 4 && n >= 16) return;
    float v;
    if (mat == 0)      v = Wf[(size_t)k * NOUT + n];
    else if (mat == 1) v = Wf[(size_t)k * NOUT + C_ + n];
    else if (mat == 2) v = Wh[(size_t)k * C_ + n];
    else if (mat == 3) v = Wp[(size_t)k * C_ + n];
    else               v = (n < 4) ? Wf[(size_t)k * NOUT + 2*C_ + n] : 0.0f;
    union { _Float16 h; ushort_t s; } ch, cl;
    ch.h = (_Float16)v;
    cl.h = (_Float16)(v - (float)ch.h);
    ushort_t* base = pk + (size_t)mat * (2 * C_ * C_);
    const int lo_off = (mat == 4) ? 16 * C_ : C_ * C_;
    base[n * C_ + k] = ch.s;
    base[lo_off + n * C_ + k] = cl.s;
}

// ---------------------------------------------------------------------------
// Per-wave split-f16 GEMM: 64(tokens) x 32(cols at n0) x K=128.
// acc layout: acc[m][n], D row = m*16 + (lane>>4)*4 + reg, col = n0+n*16+(lane&15)
// ---------------------------------------------------------------------------
template <bool A_LO>
__device__ __forceinline__ void mfma_gemm64(
    const ushort_t (*Ah)[136], const ushort_t (*Al)[136],
    const ushort_t* __restrict__ Bh, const ushort_t* __restrict__ Bl,
    int lane, int n0, f32x4 acc[4][2])
{
    const int ar = lane & 15;               // A row / B col within tile
    const int ak = (lane >> 4) << 3;        // k offset within 32-step
    #pragma unroll
    for (int kk = 0; kk < 4; ++kk) {
        const int kb = (kk << 5) + ak;
        const h16x8 bh0 = *(const h16x8*)(Bh + (((n0      + ar) << 7) + kb));
        const h16x8 bh1 = *(const h16x8*)(Bh + (((n0 + 16 + ar) << 7) + kb));
        const h16x8 bl0 = *(const h16x8*)(Bl + (((n0      + ar) << 7) + kb));
        const h16x8 bl1 = *(const h16x8*)(Bl + (((n0 + 16 + ar) << 7) + kb));
        #pragma unroll
        for (int m = 0; m < 4; ++m) {
            const h16x8 ah = *(const h16x8*)&Ah[(m << 4) + ar][kb];
            if constexpr (A_LO) {
                const h16x8 al = *(const h16x8*)&Al[(m << 4) + ar][kb];
                acc[m][0] = __builtin_amdgcn_mfma_f32_16x16x32_f16(al, bh0, acc[m][0], 0, 0, 0);
                acc[m][1] = __builtin_amdgcn_mfma_f32_16x16x32_f16(al, bh1, acc[m][1], 0, 0, 0);
            }
            acc[m][0] = __builtin_amdgcn_mfma_f32_16x16x32_f16(ah, bl0, acc[m][0], 0, 0, 0);
            acc[m][1] = __builtin_amdgcn_mfma_f32_16x16x32_f16(ah, bl1, acc[m][1], 0, 0, 0);
            acc[m][0] = __builtin_amdgcn_mfma_f32_16x16x32_f16(ah, bh0, acc[m][0], 0, 0, 0);
            acc[m][1] = __builtin_amdgcn_mfma_f32_16x16x32_f16(ah, bh1, acc[m][1], 0, 0, 0);
        }
    }
}

// stage 64x128 fp32 tile -> LDS f16 hi/lo (coalesced 32B/thread reads)
__device__ __forceinline__ void stage_split_f32(
    const float* __restrict__ src, int tid,
    ushort_t (*Ah)[136], ushort_t (*Al)[136])
{
    #pragma unroll
    for (int p = 0; p < 4; ++p) {
        const int i  = tid + (p << 8);        // 0..1023
        const int t  = i >> 4;                // token row
        const int c8 = (i & 15) << 3;         // k chunk
        const float4 v0 = *(const float4*)(src + (size_t)t * C_ + c8);
        const float4 v1 = *(const float4*)(src + (size_t)t * C_ + c8 + 4);
        const float f[8] = {v0.x, v0.y, v0.z, v0.w, v1.x, v1.y, v1.z, v1.w};
        split8_to(f, &Ah[t][c8], &Al[t][c8]);
    }
}

// ---------------------------------------------------------------------------
// K1: ctx = (x @ Wf)[:, 128:256] + bf ; gates = (x @ Wf)[:, 256:260] + bf
// ctx stored f16 transposed [C/8][NTOK][8]. gates via padded 16-col MFMA tile.
// ---------------------------------------------------------------------------
__global__ __launch_bounds__(256) void gemm_ctx_gates_mfma(
    const float* __restrict__ x, const float* __restrict__ bf,
    const ushort_t* __restrict__ pk,
    ushort_t* __restrict__ ctx, float* __restrict__ gates,
    float* __restrict__ csum)
{
    __shared__ ushort_t Abuf[2][64][136];     // hi / lo (34816 B)
    const int tid  = threadIdx.x;
    const int tok0 = blockIdx.x * 64;
    const int lane = tid & 63;
    const int n0   = (tid >> 6) << 5;         // wave's 32-col strip

    if (blockIdx.x < 8) csum[blockIdx.x * 256 + tid] = 0.0f;

    stage_split_f32(x + (size_t)tok0 * C_, tid, Abuf[0], Abuf[1]);
    __syncthreads();

    f32x4 acc[4][2] = {};
    {
        const ushort_t* Bh = pk + (size_t)1 * (2 * C_ * C_);   // mat 1 = Wf ctx cols
        const ushort_t* Bl = Bh + C_ * C_;
        mfma_gemm64<true>(Abuf[0], Abuf[1], Bh, Bl, lane, n0, acc);
    }

    // gates: wave w computes its own 16-row tile against the padded gate cols
    {
        const int w  = tid >> 6;
        const int ar = lane & 15;
        const int ak = (lane >> 4) << 3;
        const ushort_t* Gh = pk + (size_t)4 * (2 * C_ * C_);
        const ushort_t* Gl = Gh + 16 * C_;
        f32x4 gacc = {};
        #pragma unroll
        for (int kk = 0; kk < 4; ++kk) {
            const int kb = (kk << 5) + ak;
            const h16x8 gh = *(const h16x8*)(Gh + ((ar << 7) + kb));
            const h16x8 gl = *(const h16x8*)(Gl + ((ar << 7) + kb));
            const h16x8 ah = *(const h16x8*)&Abuf[0][(w << 4) + ar][kb];
            const h16x8 al = *(const h16x8*)&Abuf[1][(w << 4) + ar][kb];
            gacc = __builtin_amdgcn_mfma_f32_16x16x32_f16(al, gh, gacc, 0, 0, 0);
            gacc = __builtin_amdgcn_mfma_f32_16x16x32_f16(ah, gl, gacc, 0, 0, 0);
            gacc = __builtin_amdgcn_mfma_f32_16x16x32_f16(ah, gh, gacc, 0, 0, 0);
        }
        if (ar < 4) {
            const int rg = (lane >> 4) << 2;
            #pragma unroll
            for (int r = 0; r < 4; ++r)
                gates[(size_t)(tok0 + (w << 4) + rg + r) * 4 + ar] = gacc[r] + bf[2*C_ + ar];
        }
    }
    __syncthreads();   // all LDS reads done before overwrite

    // epilogue: acc + bias -> f16 via pkrtz pairs -> Abuf[0] as ctx_lds[64][136]
    {
        const int ar = lane & 15;
        const int rg = (lane >> 4) << 2;
        #pragma unroll
        for (int n = 0; n < 2; ++n) {
            const int col = n0 + (n << 4) + ar;
            const float bias = bf[C_ + col];
            #pragma unroll
            for (int m = 0; m < 4; ++m) {
                const int rowb = (m << 4) + rg;
                const uint_t p0 = pkh2(acc[m][n][0] + bias, acc[m][n][1] + bias);
                const uint_t p1 = pkh2(acc[m][n][2] + bias, acc[m][n][3] + bias);
                Abuf[0][rowb + 0][col] = (ushort_t)p0;
                Abuf[0][rowb + 1][col] = (ushort_t)(p0 >> 16);
                Abuf[0][rowb + 2][col] = (ushort_t)p1;
                Abuf[0][rowb + 3][col] = (ushort_t)(p1 >> 16);
            }
        }
    }
    __syncthreads();

    // coalesced transposed store: ctx[colgrp][token][8]
    #pragma unroll
    for (int p = 0; p < 4; ++p) {
        const int i  = tid + (p << 8);
        const int cg = i >> 6;
        const int t  = i & 63;
        *(uint4*)(ctx + (((size_t)cg * NTOK + tok0 + t) << 3))
            = *(const uint4*)&Abuf[0][t][cg << 3];
    }
}

// ---------------------------------------------------------------------------
// K2 (fused): conv3->gelu->conv5->gelu->conv7->gelu cascade in LDS.
// f16 data + f16 weights, f32 accumulate via v_fma_mix_f32 (no unpack ALU).
// ---------------------------------------------------------------------------
__global__ __launch_bounds__(256, 4) void focal_conv_fused(
    const ushort_t* __restrict__ ctx_in,
    const float* __restrict__ k0w, const float* __restrict__ k1w,
    const float* __restrict__ k2w,
    const float* __restrict__ gates,
    ushort_t* __restrict__ ctx_all,
    float* __restrict__ csum)
{
    __shared__ uint4 bufA[B0H*B0W];            // 19712 B (stage0 in; stage2 out 22x38)
    __shared__ uint4 buf1[B1H*B1W];            // 17472 B
    __shared__ uint_t wtsu[(9+25+49)*4];       //  1328 B  (83 taps x 8ch f16 pairs)

    const int tid  = threadIdx.x;
    const int cg   = blockIdx.x;               // 0..15 channel group
    const int tile = blockIdx.y;               // 0..17
    const int bb   = blockIdx.z;               // 0..15
    const int wt   = tile % 3, ht = tile / 3;
    const int c0   = cg << 3;
    const int h0   = ht * TH, w0 = wt * TW;

    // weights -> LDS as f16 pairs (83 taps x 8 ch)
    if (tid < 166) {
        const int f = tid << 2;
        const float* src; int r;
        if (f < 72)       { r = f;       src = k0w; }
        else if (f < 272) { r = f - 72;  src = k1w; }
        else              { r = f - 272; src = k2w; }
        const int tap = r >> 3, off = r & 7;
        const float4 v = *(const float4*)(src + tap * C_ + c0 + off);
        *(uint2*)&wtsu[f >> 1] = make_uint2(pkh2(v.x, v.y), pkh2(v.z, v.w));
    }

    // stage 0: global -> bufA (contiguous reads from transposed f16 ctx)
    const ushort_t* cin = ctx_in + (((size_t)cg * NTOK + (size_t)bb * HW_) << 3);
    for (int i = tid; i < B0H*B0W; i += 256) {
        const int r = i / B0W, q = i - r * B0W;
        const int hh = h0 - 6 + r, ww = w0 - 6 + q;
        uint4 v = make_uint4(0u, 0u, 0u, 0u);
        if ((unsigned)hh < (unsigned)H_ && (unsigned)ww < (unsigned)W_)
            v = *(const uint4*)(cin + ((size_t)(hh * W_ + ww) << 3));
        bufA[i] = v;
    }
    __syncthreads();

    // ---- stage 1: buf1 = gelu(conv3(bufA))  [26x42] ----
    {
        int iv[5], ecp[5], boff[5];
        #pragma unroll
        for (int p = 0; p < 5; ++p) {
            const int e = tid + (p << 8);
            iv[p] = (e < B1H*B1W);
            const int ec = iv[p] ? e : 0;
            ecp[p] = ec;
            boff[p] = (ec / B1W) * B0W + (ec % B1W);
        }
        float acc[5][8] = {};
        #pragma unroll 1
        for (int a = 0; a < 3; ++a) {
            #pragma unroll
            for (int b = 0; b < 3; ++b) {
                const uint4 wq = *(const uint4*)&wtsu[(a*3+b) << 2];
                const int off = a * B0W + b;
                #pragma unroll
                for (int p = 0; p < 5; ++p)
                    fmix8(acc[p], bufA[boff[p] + off], wq);
            }
        }
        __syncthreads();   // all bufA reads done before stage2 overwrites it
        #pragma unroll
        for (int p = 0; p < 5; ++p) if (iv[p]) {
            float g[8];
            #pragma unroll
            for (int c = 0; c < 8; ++c) g[c] = gelu_f(acc[p][c]);
            buf1[ecp[p]] = pkh8(g);
        }
    }
    __syncthreads();

    // ---- stage 2: bufA = gelu(conv5(buf1))  [22x38] ----
    {
        int iv[4], ecp[4], boff[4];
        #pragma unroll
        for (int p = 0; p < 4; ++p) {
            const int e = tid + (p << 8);
            iv[p] = (e < B2H*B2W);
            const int ec = iv[p] ? e : 0;
            ecp[p] = ec;
            boff[p] = (ec / B2W) * B1W + (ec % B2W);
        }
        float acc[4][8] = {};
        #pragma unroll 1
        for (int a = 0; a < 5; ++a) {
            #pragma unroll
            for (int b = 0; b < 5; ++b) {
                const uint4 wq = *(const uint4*)&wtsu[36 + ((a*5+b) << 2)];
                const int off = a * B1W + b;
                #pragma unroll
                for (int p = 0; p < 4; ++p)
                    fmix8(acc[p], buf1[boff[p] + off], wq);
            }
        }
        __syncthreads();   // bufA stage-0 data fully dead — safe to overwrite
        #pragma unroll
        for (int p = 0; p < 4; ++p) if (iv[p]) {
            float g[8];
            #pragma unroll
            for (int c = 0; c < 8; ++c) g[c] = gelu_f(acc[p][c]);
            bufA[ecp[p]] = pkh8(g);
        }
    }
    __syncthreads();

    // ---- stage 3: ctx3 = gelu(conv7(bufA)); combine 3 gated levels ----
    float lsum[8] = {};
    {
        const int th0 = tid >> 5, tw0 = tid & 31;   // p adds 8 to th
        float acc[2][8] = {};
        #pragma unroll 1
        for (int a = 0; a < 7; ++a) {
            #pragma unroll
            for (int b = 0; b < 7; ++b) {
                const uint4 wq = *(const uint4*)&wtsu[136 + ((a*7+b) << 2)];
                #pragma unroll
                for (int p = 0; p < 2; ++p) {
                    const int th = th0 + (p << 3);
                    fmix8(acc[p], bufA[(th + a)*B2W + (tw0 + b)], wq);
                }
            }
        }
        #pragma unroll
        for (int p = 0; p < 2; ++p) {
            const int th = th0 + (p << 3);
            float ctx3[8];
            #pragma unroll
            for (int c = 0; c < 8; ++c) { ctx3[c] = gelu_f(acc[p][c]); lsum[c] += ctx3[c]; }
            float d1[8]; unph8(buf1[(5+th)*B1W + (5+tw0)], d1);
            float d2[8]; unph8(bufA[(th+3)*B2W + (tw0+3)], d2);
            const size_t pix = (size_t)bb * HW_ + (size_t)(h0 + th) * W_ + (w0 + tw0);
            const float4 gt = *(const float4*)(gates + pix * 4);
            float o[8];
            #pragma unroll
            for (int c = 0; c < 8; ++c)
                o[c] = d1[c] * gt.x + d2[c] * gt.y + ctx3[c] * gt.z;
            *(uint4*)(ctx_all + pix * C_ + c0) = pkh8(o);
        }
    }

    // per-block channel sums of final ctx -> atomic accumulate
    __syncthreads();
    float* red = (float*)bufA;
    #pragma unroll
    for (int c = 0; c < 8; ++c) red[c*256 + tid] = lsum[c];
    __syncthreads();
    for (int off = 128; off > 0; off >>= 1) {
        if (tid < off) {
            #pragma unroll
            for (int c = 0; c < 8; ++c)
                red[c*256 + tid] += red[c*256 + tid + off];
        }
        __syncthreads();
    }
    if (tid < 8) atomicAdd(&csum[bb * C_ + c0 + tid], red[tid * 256]);
}

// ---------------------------------------------------------------------------
// K3: whc[b][n] = sum_k gelu(csum[b][k]/HW) * Wh[k][n]   (rank-1 factor of the
// global-context modulator)
// ---------------------------------------------------------------------------
__global__ __launch_bounds__(128) void glob_mod(
    const float* __restrict__ csum, const float* __restrict__ Wh,
    float* __restrict__ whc)
{
    __shared__ float cg[128];
    const int b = blockIdx.x, n = threadIdx.x;
    cg[n] = gelu_f(csum[b * C_ + n] * (1.0f / (float)HW_));
    __syncthreads();
    float s = 0.f;
    #pragma unroll 8
    for (int k = 0; k < C_; ++k)
        s = fmaf(cg[k], Wh[(size_t)k * C_ + n], s);
    whc[b * C_ + n] = s;
}

// ---------------------------------------------------------------------------
// K4 (fused): mod = ctx_all@Wh + g3*whc + bh ; q = x@Wf[:,:C] + bf[:C] ;
// x_out = q*mod ; LayerNorm ; out = xln@Wp + bp   — all in one block pass.
// ctx_all is exact f16 -> mod GEMM needs A-hi only (no split staging).
// ---------------------------------------------------------------------------
__global__ __launch_bounds__(256) void modq_ln_out_mfma(
    const ushort_t* __restrict__ ctx_all, const float* __restrict__ whc,
    const float* __restrict__ gates, const float* __restrict__ x,
    const ushort_t* __restrict__ pk, const float* __restrict__ bf,
    const float* __restrict__ bh, const float* __restrict__ gamma,
    const float* __restrict__ beta, const float* __restrict__ bp,
    float* __restrict__ out)
{
    __shared__ ushort_t Abuf[2][64][136];     // hi/lo staging; later aliased as xs/xln
    __shared__ float g3s[64];
    __shared__ float whcs[128];
    __shared__ float mu_s[64];
    __shared__ float rs_s[64];
    __shared__ f32x2 part[64][4];             // LN partial (s, s2) per quarter-row
    float (*xs)[132] = (float(*)[132])&Abuf[0][0][0];       // 33792 B <= 34816 B
    ushort_t (*xlnb)[136] = (ushort_t(*)[136])&Abuf[0][0][0];

    const int tid  = threadIdx.x;
    const int tok0 = blockIdx.x * 64;
    const int bidx = tok0 / HW_;
    const int lane = tid & 63;
    const int n0   = (tid >> 6) << 5;
    const int ar   = lane & 15;
    const int rg   = (lane >> 4) << 2;

    // ---- stage ctx_all (f16, no split) + g3/whc row caches ----
    #pragma unroll
    for (int p = 0; p < 4; ++p) {
        const int i  = tid + (p << 8);
        const int t  = i >> 4;
        const int c8 = (i & 15) << 3;
        *(us8*)&Abuf[0][t][c8] = *(const us8*)(ctx_all + (size_t)(tok0 + t) * C_ + c8);
    }
    if (tid < 64)           g3s[tid]        = gates[(size_t)(tok0 + tid) * 4 + 3];
    else if (tid < 192)     whcs[tid - 64]  = whc[bidx * C_ + (tid - 64)];
    __syncthreads();

    f32x4 am[4][2] = {};
    {
        const ushort_t* Bh2 = pk + (size_t)2 * (2 * C_ * C_);   // mat 2 = Wh
        const ushort_t* Bl2 = Bh2 + C_ * C_;
        mfma_gemm64<false>(Abuf[0], Abuf[0], Bh2, Bl2, lane, n0, am);
    }
    __syncthreads();   // all mod-frag reads done before restaging

    // ---- stage A_q = x, split hi/lo ----
    stage_split_f32(x + (size_t)tok0 * C_, tid, Abuf[0], Abuf[1]);
    __syncthreads();

    f32x4 aq[4][2] = {};
    {
        const ushort_t* Bh0 = pk;                                // mat 0 = Wf q cols
        const ushort_t* Bl0 = Bh0 + C_ * C_;
        mfma_gemm64<true>(Abuf[0], Abuf[1], Bh0, Bl0, lane, n0, aq);
    }
    __syncthreads();   // all q-frag reads done before xs overwrites LDS

    // ---- x_out = (q + bf) * (mod + g3*whc + bh) -> xs ----
    {
        #pragma unroll
        for (int n = 0; n < 2; ++n) {
            const int col = n0 + (n << 4) + ar;
            const float bfv = bf[col];
            const float bhv = bh[col];
            const float whv = whcs[col];
            #pragma unroll
            for (int m = 0; m < 4; ++m)
                #pragma unroll
                for (int r = 0; r < 4; ++r) {
                    const int row = (m << 4) + rg + r;
                    const float mod = am[m][n][r] + g3s[row] * whv + bhv;
                    xs[row][col] = (aq[m][n][r] + bfv) * mod;
                }
        }
    }
    __syncthreads();

    // ---- LN stats: all 256 threads, quarter-row partials ----
    {
        const int tt = tid >> 2;
        const int qq = tid & 3;
        float s = 0.f, s2 = 0.f;
        #pragma unroll
        for (int c = 0; c < 32; c += 4) {
            const float4 v = *(const float4*)&xs[tt][(qq << 5) + c];
            s  += v.x + v.y + v.z + v.w;
            s2 += v.x*v.x + v.y*v.y + v.z*v.z + v.w*v.w;
        }
        f32x2 pr; pr.x = s; pr.y = s2;
        part[tt][qq] = pr;
    }
    __syncthreads();
    if (tid < 64) {
        const f32x2 p0 = part[tid][0], p1 = part[tid][1];
        const f32x2 p2 = part[tid][2], p3 = part[tid][3];
        const float s  = (p0.x + p1.x) + (p2.x + p3.x);
        const float s2 = (p0.y + p1.y) + (p2.y + p3.y);
        const float mu  = s * (1.0f / 128.0f);
        const float var = s2 * (1.0f / 128.0f) - mu * mu;
        mu_s[tid] = mu;
        rs_s[tid] = rsqrtf(var + 0.001f);
    }
    __syncthreads();

    // ---- LN apply into registers (xs still live), then write xln f16 ----
    {
        const int tt = tid >> 2;
        const int c0b = (tid & 3) << 5;
        const float mu = mu_s[tt], rs = rs_s[tt];
        uint_t xw[16];
        #pragma unroll
        for (int j = 0; j < 8; ++j) {
            const int c = c0b + (j << 2);
            const float4 v  = *(const float4*)&xs[tt][c];
            const float4 gm = *(const float4*)(gamma + c);
            const float4 bt = *(const float4*)(beta + c);
            xw[2*j]   = pkh2((v.x - mu) * rs * gm.x + bt.x,
                             (v.y - mu) * rs * gm.y + bt.y);
            xw[2*j+1] = pkh2((v.z - mu) * rs * gm.z + bt.z,
                             (v.w - mu) * rs * gm.w + bt.w);
        }
        __syncthreads();   // all xs reads complete before overwrite
        #pragma unroll
        for (int j = 0; j < 4; ++j)
            *(uint4*)&xlnb[tt][c0b + (j << 3)] = *(uint4*)&xw[4*j];
    }
    __syncthreads();

    // ---- out = xln @ Wp + bp ----
    f32x4 ao[4][2] = {};
    {
        const ushort_t* Bh3 = pk + (size_t)3 * (2 * C_ * C_);   // mat 3 = Wp
        const ushort_t* Bl3 = Bh3 + C_ * C_;
        mfma_gemm64<false>((const ushort_t(*)[136])xlnb,
                           (const ushort_t(*)[136])xlnb, Bh3, Bl3, lane, n0, ao);
    }
    {
        #pragma unroll
        for (int n = 0; n < 2; ++n) {
            const int col = n0 + (n << 4) + ar;
            const float bpv = bp[col];
            #pragma unroll
            for (int m = 0; m < 4; ++m)
                #pragma unroll
                for (int r = 0; r < 4; ++r) {
                    const int row = (m << 4) + rg + r;
                    out[(size_t)(tok0 + row) * C_ + col] = ao[m][n][r] + bpv;
                }
        }
    }
}

// ---------------------------------------------------------------------------
extern "C" void kernel_launch(void* const* d_in, const int* in_sizes, int n_in,
                              void* d_out, int out_size, void* d_ws, size_t ws_size,
                              hipStream_t stream) {
    const float* x     = (const float*)d_in[0];
    const float* Wf    = (const float*)d_in[1];
    const float* bf    = (const float*)d_in[2];
    const float* Wh    = (const float*)d_in[3];
    const float* bh    = (const float*)d_in[4];
    const float* gamma = (const float*)d_in[5];
    const float* beta  = (const float*)d_in[6];
    const float* Wp    = (const float*)d_in[7];
    const float* bp    = (const float*)d_in[8];
    const float* k0    = (const float*)d_in[9];
    const float* k1    = (const float*)d_in[10];
    const float* k2    = (const float*)d_in[11];
    float* out = (float*)d_out;

    const size_t NC = (size_t)NTOK * C_;
    ushort_t* P0  = (ushort_t*)d_ws;          // ctx transposed (f16)
    ushort_t* ACC = P0 + NC;                  // ctx_all (token-major, f16)
    float* gates  = (float*)(ACC + NC);
    float* csum   = gates + (size_t)NTOK * 4;
    float* whc    = csum + (size_t)B_ * C_;
    ushort_t* pkw = (ushort_t*)(whc + (size_t)B_ * C_);  // 4x(2x128x128) + 2x16x128 f16

    pack_weights<<<dim3(C_, 5), 128, 0, stream>>>(Wf, Wh, Wp, pkw);
    gemm_ctx_gates_mfma<<<NTOK / 64, 256, 0, stream>>>(x, bf, pkw, P0, gates, csum);
    focal_conv_fused<<<dim3(C_/8, (H_/TH)*(W_/TW), B_), 256, 0, stream>>>(
        P0, k0, k1, k2, gates, ACC, csum);
    glob_mod<<<B_, 128, 0, stream>>>(csum, Wh, whc);
    modq_ln_out_mfma<<<NTOK / 64, 256, 0, stream>>>(
        ACC, whc, gates, x, pkw, bf, bh, gamma, beta, bp, out);
}